// Round 2
// baseline (1217.802 us; speedup 1.0000x reference)
//
#include <hip/hip_runtime.h>

typedef __bf16 bf16_t;
typedef unsigned int u32;
typedef __attribute__((ext_vector_type(8))) __bf16 bf16x8;
typedef __attribute__((ext_vector_type(4))) __bf16 bf16x4;
typedef __attribute__((ext_vector_type(4))) float f32x4;

// B=4, S=SM=1024, D=1024, H=16, HD=64, DFF=4096; M = B*S = 4096 rows.
// Inputs fp32; d_out fp32 (x, sa_k, sa_v). Internals bf16 (MFMA).
// FAST PATH (ws >= 96MB, confirmed r6): bf16 weights cached in ws.

__device__ __forceinline__ bf16x8 load8f(const float* f) {
    float4 a = *(const float4*)f;
    float4 b = *(const float4*)(f + 4);
    bf16x8 r;
    r[0] = (bf16_t)a.x; r[1] = (bf16_t)a.y; r[2] = (bf16_t)a.z; r[3] = (bf16_t)a.w;
    r[4] = (bf16_t)b.x; r[5] = (bf16_t)b.y; r[6] = (bf16_t)b.z; r[7] = (bf16_t)b.w;
    return r;
}

// async 16B/lane global->LDS; LDS dest = wave-uniform base + lane*16
__device__ __forceinline__ void gll16(const void* g, const void* l) {
    __builtin_amdgcn_global_load_lds(
        (const __attribute__((address_space(1))) u32*)(unsigned long long)g,
        (__attribute__((address_space(3))) u32*)(unsigned int)(unsigned long long)l,
        16, 0, 0);
}

// ---------------------------------------------------------------------------
// fp32 -> bf16 weight/mem conversion (one contiguous buffer).
// [0,1M) Wq | [1M,2M) Wk | [2M,3M) Wv | [3M,4M) Wo | [4M,7M) mha_in_w |
// [7M,8M) mha_out_w | [8M,12M) W1 | [12M,16M) W2 | [16M,20M) mem
// ---------------------------------------------------------------------------
__global__ __launch_bounds__(256) void conv_kernel(
    const float* __restrict__ Wq, const float* __restrict__ Wk,
    const float* __restrict__ Wv, const float* __restrict__ Wo,
    const float* __restrict__ Wio, const float* __restrict__ Woo,
    const float* __restrict__ W1, const float* __restrict__ W2,
    const float* __restrict__ mem, bf16_t* __restrict__ dst)
{
    long e = ((long)blockIdx.x * 256 + threadIdx.x) * 8;
    const float* s; long o;
    if      (e <  1048576) { s = Wq;  o = e; }
    else if (e <  2097152) { s = Wk;  o = e -  1048576; }
    else if (e <  3145728) { s = Wv;  o = e -  2097152; }
    else if (e <  4194304) { s = Wo;  o = e -  3145728; }
    else if (e <  7340032) { s = Wio; o = e -  4194304; }
    else if (e <  8388608) { s = Woo; o = e -  7340032; }
    else if (e < 12582912) { s = W1;  o = e -  8388608; }
    else if (e < 16777216) { s = W2;  o = e - 12582912; }
    else                   { s = mem; o = e - 16777216; }
    *(bf16x8*)&dst[e] = load8f(s + o);
}

// ---------------------------------------------------------------------------
// LayerNorm: one block per fp32 row of 1024 -> bf16 out (fp32 math).
// ---------------------------------------------------------------------------
__global__ __launch_bounds__(256) void ln_kernel(
    const float* __restrict__ x,
    const float* __restrict__ g, const float* __restrict__ be,
    bf16_t* __restrict__ out)
{
    int row = blockIdx.x, t = threadIdx.x;
    float4 q = *(const float4*)(x + (long)row * 1024 + t * 4);
    float v[4] = {q.x, q.y, q.z, q.w};
    float s = v[0] + v[1] + v[2] + v[3];
    float s2 = v[0]*v[0] + v[1]*v[1] + v[2]*v[2] + v[3]*v[3];
    for (int off = 32; off > 0; off >>= 1) {
        s  += __shfl_down(s, off);
        s2 += __shfl_down(s2, off);
    }
    __shared__ float rs[4], rq[4];
    int w = t >> 6;
    if ((t & 63) == 0) { rs[w] = s; rq[w] = s2; }
    __syncthreads();
    s  = rs[0] + rs[1] + rs[2] + rs[3];
    s2 = rq[0] + rq[1] + rq[2] + rq[3];
    float mean = s * (1.0f / 1024.0f);
    float var  = s2 * (1.0f / 1024.0f) - mean * mean;
    float rstd = rsqrtf(var + 1e-5f);
    int c = t * 4;
    for (int i = 0; i < 4; i++)
        out[(long)row * 1024 + c + i] =
            (bf16_t)((v[i] - mean) * rstd * g[c + i] + be[c + i]);
}

// ---------------------------------------------------------------------------
// FAST NT GEMM v3: C = A * W^T (+bias,+relu,+fp32 resid)
// 128x128 tile, BK=64, SINGLE-buffered 32KB LDS (m97 form: 2 barriers/K-step,
// overlap via 3 resident blocks/CU — the 64KB dbuf was the m132 occupancy
// trap: 2 blocks/CU), XOR-swizzled chunks, full-128B-row global_load_lds
// staging, column-major block remap (XCD-local A strips when gridDim.y%8==0).
// mode 0: o0=f32 rm | o1=b16 rm | o2=b16 head
// mode 1 (QKV): seg0->o0 b16 head; seg1->o1 f32 head (+o3 b16 head);
//               seg2->o2 f32 head (+o4 b16 head)
// mode 2 (crossKV): seg0->o0 b16 head, seg1->o1 b16 head
// ---------------------------------------------------------------------------
__global__ __launch_bounds__(256) void gemm_fast(
    const bf16_t* __restrict__ A, int lda, int a_head,
    const bf16_t* __restrict__ Wb, long w_off, int ldw, int K,
    const float* __restrict__ bias, long b_off,
    const float* resid,
    void* o0, void* o1, void* o2, int mode, int N, int do_relu,
    void* o3, void* o4)
{
    __shared__ __align__(16) bf16_t As[128 * 64];
    __shared__ __align__(16) bf16_t Bs[128 * 64];
    int tid = threadIdx.x;
    int lin = blockIdx.y * gridDim.x + blockIdx.x;   // HW dispatch order
    int mb = lin % gridDim.y, nb = lin / gridDim.y;  // m fastest -> A strip XCD-local
    int m0 = mb << 7, n0 = nb << 7;
    int w = tid >> 6, lane = tid & 63;
    int l15 = lane & 15, quad = lane >> 4;
    int wr = (w >> 1) << 6, wc = (w & 1) << 6;

    int srow = lane >> 3;                 // row within 8-row staging group
    int cgo  = ((lane & 7) ^ srow) << 3;  // swizzled source chunk offset (elems)

    f32x4 acc[4][4];
    for (int i = 0; i < 4; i++)
        for (int j = 0; j < 4; j++)
            acc[i][j] = (f32x4){0.f, 0.f, 0.f, 0.f};

    const bf16_t* Wg = Wb + w_off;
    int nk = K >> 6;

#define STAGE(KK)                                                             \
    {                                                                         \
        const bf16_t* Ab; long astr;                                          \
        if (a_head) {                                                         \
            int hh = (KK) >> 6;                                               \
            Ab = A + ((((long)(m0 >> 10)) * 16 + hh) * 1024 + (m0 & 1023)) * 64; \
            astr = 64;                                                        \
        } else {                                                              \
            Ab = A + (long)m0 * lda + (KK);                                   \
            astr = lda;                                                       \
        }                                                                     \
        const bf16_t* Bb = Wg + (long)n0 * ldw + (KK);                        \
        for (int t = 0; t < 4; t++) {                                         \
            int rb2 = (w << 5) + (t << 3);                                    \
            gll16(Ab + (long)(rb2 + srow) * astr + cgo, &As[rb2 << 6]);       \
            gll16(Bb + (long)(rb2 + srow) * ldw  + cgo, &Bs[rb2 << 6]);       \
        }                                                                     \
    }

#define COMPUTE()                                                             \
    for (int ks = 0; ks < 2; ks++) {                                          \
        bf16x8 af[4], bf_[4];                                                 \
        int gA = quad + (ks << 2);                                            \
        int sl = (gA ^ (l15 & 7)) << 3;                                       \
        for (int i = 0; i < 4; i++)                                           \
            af[i]  = *(const bf16x8*)&As[((wr + (i << 4) + l15) << 6) + sl];  \
        for (int j = 0; j < 4; j++)                                           \
            bf_[j] = *(const bf16x8*)&Bs[((wc + (j << 4) + l15) << 6) + sl];  \
        for (int i = 0; i < 4; i++)                                           \
            for (int j = 0; j < 4; j++)                                       \
                acc[i][j] = __builtin_amdgcn_mfma_f32_16x16x32_bf16(          \
                    af[i], bf_[j], acc[i][j], 0, 0, 0);                       \
    }

    for (int kt = 0; kt < nk; kt++) {
        if (kt) __syncthreads();          // prior COMPUTE done before overwrite
        STAGE(kt << 6)
        __syncthreads();                  // drains gll16 (vmcnt) + LDS visible
        COMPUTE()
    }
#undef STAGE
#undef COMPUTE

    int rb = quad << 2;  // C/D: col = lane&15, row = quad*4 + reg
    for (int i = 0; i < 4; i++) {
        for (int j = 0; j < 4; j++) {
            int col = n0 + wc + (j << 4) + l15;
            float bv = bias ? bias[b_off + col] : 0.0f;
            for (int r = 0; r < 4; r++) {
                int row = m0 + wr + (i << 4) + rb + r;
                float v = acc[i][j][r] + bv;
                if (do_relu) v = fmaxf(v, 0.0f);
                if (mode == 0) {
                    long idx = (long)row * N + col;
                    if (resid) v += resid[idx];
                    if (o0) ((float*)o0)[idx] = v;
                    if (o1) ((bf16_t*)o1)[idx] = (bf16_t)v;
                    if (o2) {
                        long hidx = (((long)(row >> 10) * 16 + (col >> 6)) * 1024
                                     + (row & 1023)) * 64 + (col & 63);
                        ((bf16_t*)o2)[hidx] = (bf16_t)v;
                    }
                } else {
                    int seg = col >> 10, c = col & 1023;
                    long hidx = (((long)(row >> 10) * 16 + (c >> 6)) * 1024
                                 + (row & 1023)) * 64 + (c & 63);
                    if (mode == 1) {
                        if (seg == 0)      ((bf16_t*)o0)[hidx] = (bf16_t)v;
                        else if (seg == 1) {
                            ((float*)o1)[hidx] = v;
                            if (o3) ((bf16_t*)o3)[hidx] = (bf16_t)v;
                        } else {
                            ((float*)o2)[hidx] = v;
                            if (o4) ((bf16_t*)o4)[hidx] = (bf16_t)v;
                        }
                    } else {
                        if (seg == 0)      ((bf16_t*)o0)[hidx] = (bf16_t)v;
                        else               ((bf16_t*)o1)[hidx] = (bf16_t)v;
                    }
                }
            }
        }
    }
}

// ---------------------------------------------------------------------------
// FALLBACK NT GEMM (round-5, fp32 weights) — only if ws < 96MB.
// ---------------------------------------------------------------------------
#define LDT 40

__global__ __launch_bounds__(256) void gemm_nt(
    const void* __restrict__ A, int lda, int a_head, int a_f32,
    const float* __restrict__ W, long w_off, int ldw,
    int K,
    const float* __restrict__ bias, long b_off,
    const float* resid,
    float*  out_f32, bf16_t* __restrict__ out_b16,
    float*  __restrict__ out_hf32, bf16_t* __restrict__ out_hb16,
    int N, int do_relu)
{
    __shared__ bf16_t As[128 * LDT];
    __shared__ bf16_t Bs[128 * LDT];
    int tid = threadIdx.x;
    int m0 = blockIdx.y << 7, n0 = blockIdx.x << 7;
    int wave = tid >> 6, lane = tid & 63;
    int wr = (wave >> 1) << 6;
    int wc = (wave & 1) << 6;
    int l15 = lane & 15, quad = lane >> 4;

    f32x4 acc[4][4];
    for (int i = 0; i < 4; i++)
        for (int j = 0; j < 4; j++)
            acc[i][j] = (f32x4){0.f, 0.f, 0.f, 0.f};

    int sr = tid >> 2;
    int sc = (tid & 3) << 3;

    for (int k0 = 0; k0 < K; k0 += 32) {
        int kk = k0 + sc;
        long ia0, ia1;
        if (a_head) {
            int hh = kk >> 6, dd = kk & 63;
            int r0g = m0 + sr, r1g = r0g + 64;
            ia0 = ((((long)(r0g >> 10) * 16 + hh) * 1024 + (r0g & 1023)) << 6) + dd;
            ia1 = ((((long)(r1g >> 10) * 16 + hh) * 1024 + (r1g & 1023)) << 6) + dd;
        } else {
            ia0 = (long)(m0 + sr) * lda + kk;
            ia1 = (long)(m0 + sr + 64) * lda + kk;
        }
        long iw0 = w_off + (long)(n0 + sr) * ldw + kk;
        long iw1 = w_off + (long)(n0 + sr + 64) * ldw + kk;
        __syncthreads();
        if (a_f32) {
            *(bf16x8*)&As[sr * LDT + sc]        = load8f((const float*)A + ia0);
            *(bf16x8*)&As[(sr + 64) * LDT + sc] = load8f((const float*)A + ia1);
        } else {
            *(bf16x8*)&As[sr * LDT + sc]        = *(const bf16x8*)((const bf16_t*)A + ia0);
            *(bf16x8*)&As[(sr + 64) * LDT + sc] = *(const bf16x8*)((const bf16_t*)A + ia1);
        }
        *(bf16x8*)&Bs[sr * LDT + sc]        = load8f(W + iw0);
        *(bf16x8*)&Bs[(sr + 64) * LDT + sc] = load8f(W + iw1);
        __syncthreads();
        bf16x8 afr[4], bfr[4];
        for (int i = 0; i < 4; i++)
            afr[i] = *(const bf16x8*)&As[(wr + i * 16 + l15) * LDT + quad * 8];
        for (int j = 0; j < 4; j++)
            bfr[j] = *(const bf16x8*)&Bs[(wc + j * 16 + l15) * LDT + quad * 8];
        for (int i = 0; i < 4; i++)
            for (int j = 0; j < 4; j++)
                acc[i][j] = __builtin_amdgcn_mfma_f32_16x16x32_bf16(
                    afr[i], bfr[j], acc[i][j], 0, 0, 0);
    }

    int rb = quad << 2;
    for (int i = 0; i < 4; i++) {
        for (int j = 0; j < 4; j++) {
            int col = n0 + wc + (j << 4) + l15;
            float bv = bias ? bias[b_off + col] : 0.0f;
            for (int r = 0; r < 4; r++) {
                int row = m0 + wr + (i << 4) + rb + r;
                float v = acc[i][j][r] + bv;
                if (do_relu) v = fmaxf(v, 0.0f);
                long idx = (long)row * N + col;
                if (resid) v += resid[idx];
                if (out_f32) out_f32[idx] = v;
                if (out_b16) out_b16[idx] = (bf16_t)v;
                if (out_hf32 || out_hb16) {
                    int bb = row >> 10, ss = row & 1023, hh = col >> 6, dd = col & 63;
                    long hidx = (((long)bb * 16 + hh) * 1024 + ss) * 64 + dd;
                    if (out_hf32) out_hf32[hidx] = v;
                    if (out_hb16) out_hb16[hidx] = (bf16_t)v;
                }
            }
        }
    }
}

// ---------------------------------------------------------------------------
// MFMA flash attention. Q bf16 head [B*H,S,64]; K/V head layout, bf16 or
// fp32 per kv_f32. Output bf16 in-place over Q.
// 4 waves/block; wave w owns Q rows [w*16, w*16+16) of a 64-row tile.
// Fragment layout mirrors gemm_fast (harness-verified): A row=l15,
// k-chunk=quad*8+ks*32; C/D row=quad*4+reg, col=l15.
// LDS tiles bf16 stride 72 (144B row = 9x16B: aligned b128 reads, bank
// step 4/row -> 2-way = free). V staged transposed so PV is NT like QK^T.
// Scale 1/sqrt(64) folded into f32 scores.
// ---------------------------------------------------------------------------
__global__ __launch_bounds__(256) void attn_kernel(
    const bf16_t* __restrict__ Q, const void* __restrict__ K,
    const void* __restrict__ V, bf16_t* __restrict__ AO,
    int Sk, int causal, int kv_f32)
{
    __shared__ __align__(16) bf16_t Qs[64 * 72];
    __shared__ __align__(16) bf16_t Ks[64 * 72];
    __shared__ __align__(16) bf16_t Vt[64 * 72];   // transposed: Vt[d][k]
    __shared__ __align__(16) bf16_t Ps[64 * 72];

    int tid = threadIdx.x;
    int qt = blockIdx.x, bh = blockIdx.y;
    int w = tid >> 6, lane = tid & 63;
    int l15 = lane & 15, quad = lane >> 4;
    int wr = w << 4;                 // wave's 16-row strip
    int rowq = wr + (quad << 2);     // this lane's 4 accumulator rows

    // ---- stage Q tile (fully coalesced: elems [tid*16, tid*16+16)) ----
    {
        int r = tid >> 2, c16 = (tid & 3) << 4;
        const bf16_t* Qb = Q + ((long)bh * 1024 + qt * 64) * 64;
        bf16x8 a = *(const bf16x8*)&Qb[r * 64 + c16];
        bf16x8 b = *(const bf16x8*)&Qb[r * 64 + c16 + 8];
        *(bf16x8*)&Qs[r * 72 + c16] = a;
        *(bf16x8*)&Qs[r * 72 + c16 + 8] = b;
    }

    float m_i[4] = {-1e30f, -1e30f, -1e30f, -1e30f};
    float l_i[4] = {0.f, 0.f, 0.f, 0.f};
    f32x4 o_acc[4];
    for (int j = 0; j < 4; j++) o_acc[j] = (f32x4){0.f, 0.f, 0.f, 0.f};

    int nt = causal ? (qt + 1) : (Sk >> 6);
    long kvbase = (long)bh * Sk * 64;

    for (int kt = 0; kt < nt; kt++) {
        __syncthreads();   // previous iter's Ks/Vt/Ps fully consumed
        {
            int r = tid >> 2, c16 = (tid & 3) << 4;
            long off = kvbase + (long)((kt << 6) + r) * 64 + c16;
            bf16x8 k0, k1, v0, v1;
            if (kv_f32) {
                const float* kp = (const float*)K + off;
                const float* vp = (const float*)V + off;
                k0 = load8f(kp); k1 = load8f(kp + 8);
                v0 = load8f(vp); v1 = load8f(vp + 8);
            } else {
                k0 = *(const bf16x8*)((const bf16_t*)K + off);
                k1 = *(const bf16x8*)((const bf16_t*)K + off + 8);
                v0 = *(const bf16x8*)((const bf16_t*)V + off);
                v1 = *(const bf16x8*)((const bf16_t*)V + off + 8);
            }
            *(bf16x8*)&Ks[r * 72 + c16] = k0;
            *(bf16x8*)&Ks[r * 72 + c16 + 8] = k1;
            for (int i = 0; i < 8; i++) {
                Vt[(c16 + i) * 72 + r]     = v0[i];
                Vt[(c16 + 8 + i) * 72 + r] = v1[i];
            }
        }
        __syncthreads();

        // ---- scores: S = (Q K^T) * 0.125 ----
        f32x4 s[4];
        for (int j = 0; j < 4; j++) s[j] = (f32x4){0.f, 0.f, 0.f, 0.f};
        for (int ks = 0; ks < 2; ks++) {
            int sl = (quad + (ks << 2)) << 3;
            bf16x8 aq = *(const bf16x8*)&Qs[(wr + l15) * 72 + sl];
            for (int j = 0; j < 4; j++) {
                bf16x8 bk = *(const bf16x8*)&Ks[((j << 4) + l15) * 72 + sl];
                s[j] = __builtin_amdgcn_mfma_f32_16x16x32_bf16(aq, bk, s[j], 0, 0, 0);
            }
        }

        // ---- online softmax (rows rowq..rowq+3, cols j*16+l15) ----
        int diag = causal && (kt == qt);
        for (int rr = 0; rr < 4; rr++) {
            float sv[4];
            for (int j = 0; j < 4; j++) {
                float x = s[j][rr] * 0.125f;
                if (diag && ((j << 4) + l15 > rowq + rr)) x = -1e30f;
                sv[j] = x;
            }
            float mx = fmaxf(fmaxf(sv[0], sv[1]), fmaxf(sv[2], sv[3]));
            for (int off = 1; off < 16; off <<= 1) mx = fmaxf(mx, __shfl_xor(mx, off));
            float mnew = fmaxf(m_i[rr], mx);
            float alpha = __expf(m_i[rr] - mnew);
            float p0 = __expf(sv[0] - mnew), p1 = __expf(sv[1] - mnew);
            float p2 = __expf(sv[2] - mnew), p3 = __expf(sv[3] - mnew);
            float rsum = p0 + p1 + p2 + p3;
            for (int off = 1; off < 16; off <<= 1) rsum += __shfl_xor(rsum, off);
            m_i[rr] = mnew;
            l_i[rr] = l_i[rr] * alpha + rsum;
            for (int j = 0; j < 4; j++) o_acc[j][rr] *= alpha;
            bf16_t* pr = &Ps[(rowq + rr) * 72 + l15];
            pr[0]  = (bf16_t)p0; pr[16] = (bf16_t)p1;
            pr[32] = (bf16_t)p2; pr[48] = (bf16_t)p3;
        }
        __syncthreads();

        // ---- O += P V  (A = Ps rows [own wave strip], B = Vt rows) ----
        for (int ks = 0; ks < 2; ks++) {
            int sl = (quad + (ks << 2)) << 3;
            bf16x8 ap = *(const bf16x8*)&Ps[(wr + l15) * 72 + sl];
            for (int j = 0; j < 4; j++) {
                bf16x8 bv = *(const bf16x8*)&Vt[((j << 4) + l15) * 72 + sl];
                o_acc[j] = __builtin_amdgcn_mfma_f32_16x16x32_bf16(ap, bv, o_acc[j], 0, 0, 0);
            }
        }
    }

    bf16_t* Ob = AO + ((long)bh * 1024 + qt * 64) * 64;
    for (int rr = 0; rr < 4; rr++) {
        float inv = 1.0f / l_i[rr];
        for (int j = 0; j < 4; j++)
            Ob[(rowq + rr) * 64 + (j << 4) + l15] = (bf16_t)(o_acc[rr >= 0 ? j : j][rr] * inv);
    }
}

// ---------------------------------------------------------------------------
extern "C" void kernel_launch(void* const* d_in, const int* in_sizes, int n_in,
                              void* d_out, int out_size, void* d_ws, size_t ws_size,
                              hipStream_t stream)
{
    (void)in_sizes; (void)n_in; (void)out_size;
    const float* tgt       = (const float*)d_in[0];
    const float* mem       = (const float*)d_in[1];
    const float* Wq        = (const float*)d_in[2];
    const float* Wk        = (const float*)d_in[3];
    const float* Wv        = (const float*)d_in[4];
    const float* Wo        = (const float*)d_in[5];
    const float* mha_in_w  = (const float*)d_in[6];
    const float* mha_in_b  = (const float*)d_in[7];
    const float* mha_out_w = (const float*)d_in[8];
    const float* mha_out_b = (const float*)d_in[9];
    const float* W1        = (const float*)d_in[10];
    const float* b1        = (const float*)d_in[11];
    const float* W2        = (const float*)d_in[12];
    const float* b2        = (const float*)d_in[13];
    const float* g1        = (const float*)d_in[14];
    const float* be1       = (const float*)d_in[15];
    const float* g2        = (const float*)d_in[16];
    const float* be2       = (const float*)d_in[17];
    const float* g3        = (const float*)d_in[18];
    const float* be3       = (const float*)d_in[19];

    float* out_x = (float*)d_out;
    float* out_k = out_x + (1 << 22);
    float* out_v = out_k + (1 << 22);

    bf16_t* R0 = (bf16_t*)d_ws;
    bf16_t* R1 = R0 + (1 << 22);
    bf16_t* R2 = R1 + (1 << 22);

    dim3 blk(256);
    dim3 gA(16, 64);

    if (ws_size >= ((size_t)96 << 20)) {
        // ---------------- FAST PATH ----------------
        bf16_t* Hff  = R2 + (1 << 22);                              // [24,56) MB
        bf16_t* Wb   = (bf16_t*)((char*)d_ws + ((size_t)56 << 20)); // [56,88)
        bf16_t* memb = Wb + 16777216;                               // [88,96)
        // bf16 self-attn K/V copies live in the Hff region (free until FFN):
        bf16_t* saKb = Hff;                 // [24,32) MB
        bf16_t* saVb = Hff + (1 << 22);     // [32,40) MB
        const long WO_OFF  = 3145728;
        const long CQ_OFF  = 4194304;
        const long CKV_OFF = 5242880;
        const long CO_OFF  = 7340032;
        const long W1_OFF  = 8388608;
        const long W2_OFF  = 12582912;

        conv_kernel<<<10240, blk, 0, stream>>>(Wq, Wk, Wv, Wo, mha_in_w,
                                               mha_out_w, W1, W2, mem, Wb);

        // ---- self-attention ----
        ln_kernel<<<4096, blk, 0, stream>>>(tgt, g1, be1, R0);
        gemm_fast<<<dim3(24, 32), blk, 0, stream>>>(R0, 1024, 0, Wb, 0, 1024, 1024,
                                                    nullptr, 0, nullptr,
                                                    R1, out_k, out_v, 1, 3072, 0,
                                                    saKb, saVb);
        attn_kernel<<<gA, blk, 0, stream>>>(R1, saKb, saVb, R1, 1024, 1, 0);
        gemm_fast<<<dim3(8, 32), blk, 0, stream>>>(R1, 0, 1, Wb, WO_OFF, 1024, 1024,
                                                   nullptr, 0, tgt,
                                                   out_x, nullptr, nullptr, 0, 1024, 0,
                                                   nullptr, nullptr);

        // ---- cross-attention ----
        ln_kernel<<<4096, blk, 0, stream>>>(out_x, g2, be2, R0);
        gemm_fast<<<dim3(8, 32), blk, 0, stream>>>(R0, 1024, 0, Wb, CQ_OFF, 1024, 1024,
                                                   mha_in_b, 0, nullptr,
                                                   nullptr, nullptr, R1, 0, 1024, 0,
                                                   nullptr, nullptr);
        gemm_fast<<<dim3(16, 32), blk, 0, stream>>>(memb, 1024, 0, Wb, CKV_OFF, 1024, 1024,
                                                    mha_in_b, 1024, nullptr,
                                                    R2, R0, nullptr, 2, 2048, 0,
                                                    nullptr, nullptr);
        attn_kernel<<<gA, blk, 0, stream>>>(R1, R2, R0, R1, 1024, 0, 0);
        gemm_fast<<<dim3(8, 32), blk, 0, stream>>>(R1, 0, 1, Wb, CO_OFF, 1024, 1024,
                                                   mha_out_b, 0, out_x,
                                                   out_x, nullptr, nullptr, 0, 1024, 0,
                                                   nullptr, nullptr);

        // ---- FFN ----
        ln_kernel<<<4096, blk, 0, stream>>>(out_x, g3, be3, R0);
        gemm_fast<<<dim3(32, 32), blk, 0, stream>>>(R0, 1024, 0, Wb, W1_OFF, 1024, 1024,
                                                    b1, 0, nullptr,
                                                    nullptr, Hff, nullptr, 0, 4096, 1,
                                                    nullptr, nullptr);
        gemm_fast<<<dim3(8, 32), blk, 0, stream>>>(Hff, 4096, 0, Wb, W2_OFF, 4096, 4096,
                                                   b2, 0, out_x,
                                                   out_x, nullptr, nullptr, 0, 1024, 0,
                                                   nullptr, nullptr);
        return;
    }

    // ---------------- FALLBACK (round-5, known passing) ----------------
    dim3 gD(8, 32);
    dim3 gF1(32, 16);
    dim3 gF2(8, 16);

    ln_kernel<<<4096, blk, 0, stream>>>(tgt, g1, be1, R0);
    gemm_nt<<<gD, blk, 0, stream>>>(R0, 1024, 0, 0, Wq, 0, 1024, 1024,
                                    nullptr, 0, nullptr, nullptr, nullptr,
                                    nullptr, R1, 1024, 0);
    gemm_nt<<<gD, blk, 0, stream>>>(R0, 1024, 0, 0, Wk, 0, 1024, 1024,
                                    nullptr, 0, nullptr, nullptr, nullptr,
                                    out_k, nullptr, 1024, 0);
    gemm_nt<<<gD, blk, 0, stream>>>(R0, 1024, 0, 0, Wv, 0, 1024, 1024,
                                    nullptr, 0, nullptr, nullptr, nullptr,
                                    out_v, nullptr, 1024, 0);
    attn_kernel<<<gA, blk, 0, stream>>>(R1, out_k, out_v, R1, 1024, 1, 1);
    gemm_nt<<<gD, blk, 0, stream>>>(R1, 0, 1, 0, Wo, 0, 1024, 1024,
                                    nullptr, 0, tgt, out_x, nullptr,
                                    nullptr, nullptr, 1024, 0);

    ln_kernel<<<4096, blk, 0, stream>>>(out_x, g2, be2, R0);
    gemm_nt<<<gD, blk, 0, stream>>>(R0, 1024, 0, 0, mha_in_w, 0, 1024, 1024,
                                    mha_in_b, 0, nullptr, nullptr, nullptr,
                                    nullptr, R1, 1024, 0);
    gemm_nt<<<gD, blk, 0, stream>>>(mem, 1024, 0, 1, mha_in_w, (long)1 << 20, 1024, 1024,
                                    mha_in_b, 1024, nullptr, nullptr, nullptr,
                                    nullptr, R2, 1024, 0);
    gemm_nt<<<gD, blk, 0, stream>>>(mem, 1024, 0, 1, mha_in_w, (long)2 << 20, 1024, 1024,
                                    mha_in_b, 2048, nullptr, nullptr, nullptr,
                                    nullptr, R0, 1024, 0);
    attn_kernel<<<gA, blk, 0, stream>>>(R1, R2, R0, R1, 1024, 0, 0);
    gemm_nt<<<gD, blk, 0, stream>>>(R1, 0, 1, 0, mha_out_w, 0, 1024, 1024,
                                    mha_out_b, 0, out_x, out_x, nullptr,
                                    nullptr, nullptr, 1024, 0);

    ln_kernel<<<4096, blk, 0, stream>>>(out_x, g3, be3, R0);
    for (int c = 0; c < 2; c++) {
        const bf16_t* Ac = R0 + (long)c * 2048 * 1024;
        bf16_t*       Hc = R1;
        float*        Xc = out_x + (long)c * 2048 * 1024;
        gemm_nt<<<gF1, blk, 0, stream>>>(Ac, 1024, 0, 0, W1, 0, 1024, 1024,
                                         b1, 0, nullptr, nullptr, Hc,
                                         nullptr, nullptr, 4096, 1);
        gemm_nt<<<gF2, blk, 0, stream>>>(Hc, 4096, 0, 0, W2, 0, 4096, 4096,
                                         b2, 0, Xc, Xc, nullptr,
                                         nullptr, nullptr, 1024, 0);
    }
}

// Round 3
// 868.460 us; speedup vs baseline: 1.4023x; 1.4023x over previous
//
#include <hip/hip_runtime.h>

typedef __bf16 bf16_t;
typedef unsigned int u32;
typedef __attribute__((ext_vector_type(8))) __bf16 bf16x8;
typedef __attribute__((ext_vector_type(4))) __bf16 bf16x4;
typedef __attribute__((ext_vector_type(4))) float f32x4;

// B=4, S=SM=1024, D=1024, H=16, HD=64, DFF=4096; M = B*S = 4096 rows.
// Inputs fp32; d_out fp32 (x, sa_k, sa_v). Internals bf16 (MFMA).
// FAST PATH (ws >= 96MB): bf16 weights cached in ws.

__device__ __forceinline__ bf16x8 load8f(const float* f) {
    float4 a = *(const float4*)f;
    float4 b = *(const float4*)(f + 4);
    bf16x8 r;
    r[0] = (bf16_t)a.x; r[1] = (bf16_t)a.y; r[2] = (bf16_t)a.z; r[3] = (bf16_t)a.w;
    r[4] = (bf16_t)b.x; r[5] = (bf16_t)b.y; r[6] = (bf16_t)b.z; r[7] = (bf16_t)b.w;
    return r;
}

// async 16B/lane global->LDS; LDS dest = wave-uniform base + lane*16
__device__ __forceinline__ void gll16(const void* g, const void* l) {
    __builtin_amdgcn_global_load_lds(
        (const __attribute__((address_space(1))) u32*)(unsigned long long)g,
        (__attribute__((address_space(3))) u32*)(unsigned int)(unsigned long long)l,
        16, 0, 0);
}

// ---------------------------------------------------------------------------
// fp32 -> bf16 weight/mem conversion (one contiguous buffer).
// [0,1M) Wq | [1M,2M) Wk | [2M,3M) Wv | [3M,4M) Wo | [4M,7M) mha_in_w |
// [7M,8M) mha_out_w | [8M,12M) W1 | [12M,16M) W2 | [16M,20M) mem
// ---------------------------------------------------------------------------
__global__ __launch_bounds__(256) void conv_kernel(
    const float* __restrict__ Wq, const float* __restrict__ Wk,
    const float* __restrict__ Wv, const float* __restrict__ Wo,
    const float* __restrict__ Wio, const float* __restrict__ Woo,
    const float* __restrict__ W1, const float* __restrict__ W2,
    const float* __restrict__ mem, bf16_t* __restrict__ dst)
{
    long e = ((long)blockIdx.x * 256 + threadIdx.x) * 8;
    const float* s; long o;
    if      (e <  1048576) { s = Wq;  o = e; }
    else if (e <  2097152) { s = Wk;  o = e -  1048576; }
    else if (e <  3145728) { s = Wv;  o = e -  2097152; }
    else if (e <  4194304) { s = Wo;  o = e -  3145728; }
    else if (e <  7340032) { s = Wio; o = e -  4194304; }
    else if (e <  8388608) { s = Woo; o = e -  7340032; }
    else if (e < 12582912) { s = W1;  o = e -  8388608; }
    else if (e < 16777216) { s = W2;  o = e - 12582912; }
    else                   { s = mem; o = e - 16777216; }
    *(bf16x8*)&dst[e] = load8f(s + o);
}

// ---------------------------------------------------------------------------
// LayerNorm: one block per fp32 row of 1024 -> bf16 out (fp32 math).
// ---------------------------------------------------------------------------
__global__ __launch_bounds__(256) void ln_kernel(
    const float* __restrict__ x,
    const float* __restrict__ g, const float* __restrict__ be,
    bf16_t* __restrict__ out)
{
    int row = blockIdx.x, t = threadIdx.x;
    float4 q = *(const float4*)(x + (long)row * 1024 + t * 4);
    float v[4] = {q.x, q.y, q.z, q.w};
    float s = v[0] + v[1] + v[2] + v[3];
    float s2 = v[0]*v[0] + v[1]*v[1] + v[2]*v[2] + v[3]*v[3];
    for (int off = 32; off > 0; off >>= 1) {
        s  += __shfl_down(s, off);
        s2 += __shfl_down(s2, off);
    }
    __shared__ float rs[4], rq[4];
    int w = t >> 6;
    if ((t & 63) == 0) { rs[w] = s; rq[w] = s2; }
    __syncthreads();
    s  = rs[0] + rs[1] + rs[2] + rs[3];
    s2 = rq[0] + rq[1] + rq[2] + rq[3];
    float mean = s * (1.0f / 1024.0f);
    float var  = s2 * (1.0f / 1024.0f) - mean * mean;
    float rstd = rsqrtf(var + 1e-5f);
    int c = t * 4;
    for (int i = 0; i < 4; i++)
        out[(long)row * 1024 + c + i] =
            (bf16_t)((v[i] - mean) * rstd * g[c + i] + be[c + i]);
}

// ---------------------------------------------------------------------------
// FAST NT GEMM v4: C = A * W^T (+bias,+relu,+fp32 resid)
// Templated BN = NJ*32 (NJ=4: 128x128 tile; NJ=2: 128x64 tile for N=1024
// GEMMs -> 512-block grids, 2-3 blocks/CU instead of 1 — r2 post-mortem:
// (8,32) grids were latency-bound at 11% occupancy / 2.6 TB/s).
// BK=64, DOUBLE-buffered LDS (r2 proved prefetch-before-compute beats
// single-buffer at low block/CU counts), XOR-swizzled chunks, full-row
// global_load_lds staging, column-major block remap (XCD-local A strips
// when gridDim.y % 8 == 0).
// mode 0: o0=f32 rm | o1=b16 rm | o2=b16 head
// mode 1 (QKV): seg0->o0 b16 head; seg1->o1 f32 head (+o3 b16 head);
//               seg2->o2 f32 head (+o4 b16 head)
// mode 2 (crossKV): seg0->o0 b16 head, seg1->o1 b16 head
// ---------------------------------------------------------------------------
template<int NJ>
__global__ __launch_bounds__(256) void gemm_fast(
    const bf16_t* __restrict__ A, int lda, int a_head,
    const bf16_t* __restrict__ Wb, long w_off, int ldw, int K,
    const float* __restrict__ bias, long b_off,
    const float* resid,
    void* o0, void* o1, void* o2, int mode, int N, int do_relu,
    void* o3, void* o4)
{
    constexpr int BN = NJ << 5;           // 128 or 64
    __shared__ __align__(16) bf16_t As[2][128 * 64];
    __shared__ __align__(16) bf16_t Bs[2][BN * 64];
    int tid = threadIdx.x;
    int lin = blockIdx.y * gridDim.x + blockIdx.x;   // HW dispatch order
    int mb = lin % gridDim.y, nb = lin / gridDim.y;  // m fastest -> A strip XCD-local
    int m0 = mb << 7, n0 = nb * BN;
    int w = tid >> 6, lane = tid & 63;
    int l15 = lane & 15, quad = lane >> 4;
    int wr = (w >> 1) << 6, wc = (w & 1) * (BN >> 1);

    int srow = lane >> 3;                 // row within 8-row staging group
    int cgo  = ((lane & 7) ^ srow) << 3;  // swizzled source chunk offset (elems)

    f32x4 acc[4][NJ];
    for (int i = 0; i < 4; i++)
        for (int j = 0; j < NJ; j++)
            acc[i][j] = (f32x4){0.f, 0.f, 0.f, 0.f};

    const bf16_t* Wg = Wb + w_off;
    int nk = K >> 6;

#define STAGE(P, KK)                                                          \
    {                                                                         \
        const bf16_t* Ab; long astr;                                          \
        if (a_head) {                                                         \
            int hh = (KK) >> 6;                                               \
            Ab = A + ((((long)(m0 >> 10)) * 16 + hh) * 1024 + (m0 & 1023)) * 64; \
            astr = 64;                                                        \
        } else {                                                              \
            Ab = A + (long)m0 * lda + (KK);                                   \
            astr = lda;                                                       \
        }                                                                     \
        const bf16_t* Bb = Wg + (long)n0 * ldw + (KK);                        \
        for (int t = 0; t < 4; t++) {                                         \
            int rb2 = (w << 5) + (t << 3);                                    \
            gll16(Ab + (long)(rb2 + srow) * astr + cgo, &As[P][rb2 << 6]);    \
        }                                                                     \
        for (int t = 0; t < NJ; t++) {                                        \
            int rb2 = w * (BN >> 2) + (t << 3);                               \
            gll16(Bb + (long)(rb2 + srow) * ldw + cgo, &Bs[P][rb2 << 6]);     \
        }                                                                     \
    }

#define COMPUTE(P)                                                            \
    for (int ks = 0; ks < 2; ks++) {                                          \
        bf16x8 af[4], bf_[NJ];                                                \
        int gA = quad + (ks << 2);                                            \
        int sl = (gA ^ (l15 & 7)) << 3;                                       \
        for (int i = 0; i < 4; i++)                                           \
            af[i]  = *(const bf16x8*)&As[P][((wr + (i << 4) + l15) << 6) + sl]; \
        for (int j = 0; j < NJ; j++)                                          \
            bf_[j] = *(const bf16x8*)&Bs[P][((wc + (j << 4) + l15) << 6) + sl]; \
        for (int i = 0; i < 4; i++)                                           \
            for (int j = 0; j < NJ; j++)                                      \
                acc[i][j] = __builtin_amdgcn_mfma_f32_16x16x32_bf16(          \
                    af[i], bf_[j], acc[i][j], 0, 0, 0);                       \
    }

    STAGE(0, 0)
    __syncthreads();
    int p = 0;
    for (int kt = 0; kt < nk; kt++) {
        if (kt + 1 < nk) STAGE(p ^ 1, (kt + 1) << 6)
        COMPUTE(p)
        __syncthreads();
        p ^= 1;
    }
#undef STAGE
#undef COMPUTE

    int rb = quad << 2;  // C/D: col = lane&15, row = quad*4 + reg
    for (int i = 0; i < 4; i++) {
        for (int j = 0; j < NJ; j++) {
            int col = n0 + wc + (j << 4) + l15;
            float bv = bias ? bias[b_off + col] : 0.0f;
            for (int r = 0; r < 4; r++) {
                int row = m0 + wr + (i << 4) + rb + r;
                float v = acc[i][j][r] + bv;
                if (do_relu) v = fmaxf(v, 0.0f);
                if (mode == 0) {
                    long idx = (long)row * N + col;
                    if (resid) v += resid[idx];
                    if (o0) ((float*)o0)[idx] = v;
                    if (o1) ((bf16_t*)o1)[idx] = (bf16_t)v;
                    if (o2) {
                        long hidx = (((long)(row >> 10) * 16 + (col >> 6)) * 1024
                                     + (row & 1023)) * 64 + (col & 63);
                        ((bf16_t*)o2)[hidx] = (bf16_t)v;
                    }
                } else {
                    int seg = col >> 10, c = col & 1023;
                    long hidx = (((long)(row >> 10) * 16 + (c >> 6)) * 1024
                                 + (row & 1023)) * 64 + (c & 63);
                    if (mode == 1) {
                        if (seg == 0)      ((bf16_t*)o0)[hidx] = (bf16_t)v;
                        else if (seg == 1) {
                            ((float*)o1)[hidx] = v;
                            if (o3) ((bf16_t*)o3)[hidx] = (bf16_t)v;
                        } else {
                            ((float*)o2)[hidx] = v;
                            if (o4) ((bf16_t*)o4)[hidx] = (bf16_t)v;
                        }
                    } else {
                        if (seg == 0)      ((bf16_t*)o0)[hidx] = (bf16_t)v;
                        else               ((bf16_t*)o1)[hidx] = (bf16_t)v;
                    }
                }
            }
        }
    }
}

// ---------------------------------------------------------------------------
// FALLBACK NT GEMM (round-5, fp32 weights) — only if ws < 96MB.
// ---------------------------------------------------------------------------
#define LDT 40

__global__ __launch_bounds__(256) void gemm_nt(
    const void* __restrict__ A, int lda, int a_head, int a_f32,
    const float* __restrict__ W, long w_off, int ldw,
    int K,
    const float* __restrict__ bias, long b_off,
    const float* resid,
    float*  out_f32, bf16_t* __restrict__ out_b16,
    float*  __restrict__ out_hf32, bf16_t* __restrict__ out_hb16,
    int N, int do_relu)
{
    __shared__ bf16_t As[128 * LDT];
    __shared__ bf16_t Bs[128 * LDT];
    int tid = threadIdx.x;
    int m0 = blockIdx.y << 7, n0 = blockIdx.x << 7;
    int wave = tid >> 6, lane = tid & 63;
    int wr = (wave >> 1) << 6;
    int wc = (wave & 1) << 6;
    int l15 = lane & 15, quad = lane >> 4;

    f32x4 acc[4][4];
    for (int i = 0; i < 4; i++)
        for (int j = 0; j < 4; j++)
            acc[i][j] = (f32x4){0.f, 0.f, 0.f, 0.f};

    int sr = tid >> 2;
    int sc = (tid & 3) << 3;

    for (int k0 = 0; k0 < K; k0 += 32) {
        int kk = k0 + sc;
        long ia0, ia1;
        if (a_head) {
            int hh = kk >> 6, dd = kk & 63;
            int r0g = m0 + sr, r1g = r0g + 64;
            ia0 = ((((long)(r0g >> 10) * 16 + hh) * 1024 + (r0g & 1023)) << 6) + dd;
            ia1 = ((((long)(r1g >> 10) * 16 + hh) * 1024 + (r1g & 1023)) << 6) + dd;
        } else {
            ia0 = (long)(m0 + sr) * lda + kk;
            ia1 = (long)(m0 + sr + 64) * lda + kk;
        }
        long iw0 = w_off + (long)(n0 + sr) * ldw + kk;
        long iw1 = w_off + (long)(n0 + sr + 64) * ldw + kk;
        __syncthreads();
        if (a_f32) {
            *(bf16x8*)&As[sr * LDT + sc]        = load8f((const float*)A + ia0);
            *(bf16x8*)&As[(sr + 64) * LDT + sc] = load8f((const float*)A + ia1);
        } else {
            *(bf16x8*)&As[sr * LDT + sc]        = *(const bf16x8*)((const bf16_t*)A + ia0);
            *(bf16x8*)&As[(sr + 64) * LDT + sc] = *(const bf16x8*)((const bf16_t*)A + ia1);
        }
        *(bf16x8*)&Bs[sr * LDT + sc]        = load8f(W + iw0);
        *(bf16x8*)&Bs[(sr + 64) * LDT + sc] = load8f(W + iw1);
        __syncthreads();
        bf16x8 afr[4], bfr[4];
        for (int i = 0; i < 4; i++)
            afr[i] = *(const bf16x8*)&As[(wr + i * 16 + l15) * LDT + quad * 8];
        for (int j = 0; j < 4; j++)
            bfr[j] = *(const bf16x8*)&Bs[(wc + j * 16 + l15) * LDT + quad * 8];
        for (int i = 0; i < 4; i++)
            for (int j = 0; j < 4; j++)
                acc[i][j] = __builtin_amdgcn_mfma_f32_16x16x32_bf16(
                    afr[i], bfr[j], acc[i][j], 0, 0, 0);
    }

    int rb = quad << 2;
    for (int i = 0; i < 4; i++) {
        for (int j = 0; j < 4; j++) {
            int col = n0 + wc + (j << 4) + l15;
            float bv = bias ? bias[b_off + col] : 0.0f;
            for (int r = 0; r < 4; r++) {
                int row = m0 + wr + (i << 4) + rb + r;
                float v = acc[i][j][r] + bv;
                if (do_relu) v = fmaxf(v, 0.0f);
                long idx = (long)row * N + col;
                if (resid) v += resid[idx];
                if (out_f32) out_f32[idx] = v;
                if (out_b16) out_b16[idx] = (bf16_t)v;
                if (out_hf32 || out_hb16) {
                    int bb = row >> 10, ss = row & 1023, hh = col >> 6, dd = col & 63;
                    long hidx = (((long)bb * 16 + hh) * 1024 + ss) * 64 + dd;
                    if (out_hf32) out_hf32[hidx] = v;
                    if (out_hb16) out_hb16[hidx] = (bf16_t)v;
                }
            }
        }
    }
}

// ---------------------------------------------------------------------------
// MFMA flash attention. Q bf16 head [B*H,S,64]; K/V head layout, bf16 or
// fp32 per kv_f32. Output bf16 in-place over Q.
// 4 waves/block; wave w owns Q rows [w*16, w*16+16) of a 64-row tile.
// Fragment layout mirrors gemm_fast (harness-verified): A row=l15,
// k-chunk=quad*8+ks*32; C/D row=quad*4+reg, col=l15.
// LDS tiles bf16 stride 72 (144B row = 9x16B: aligned b128 reads, bank
// step 4/row -> 2-way = free). V staged transposed so PV is NT like QK^T.
// Scale 1/sqrt(64) folded into f32 scores.
// ---------------------------------------------------------------------------
__global__ __launch_bounds__(256) void attn_kernel(
    const bf16_t* __restrict__ Q, const void* __restrict__ K,
    const void* __restrict__ V, bf16_t* __restrict__ AO,
    int Sk, int causal, int kv_f32)
{
    __shared__ __align__(16) bf16_t Qs[64 * 72];
    __shared__ __align__(16) bf16_t Ks[64 * 72];
    __shared__ __align__(16) bf16_t Vt[64 * 72];   // transposed: Vt[d][k]
    __shared__ __align__(16) bf16_t Ps[64 * 72];

    int tid = threadIdx.x;
    int qt = blockIdx.x, bh = blockIdx.y;
    int w = tid >> 6, lane = tid & 63;
    int l15 = lane & 15, quad = lane >> 4;
    int wr = w << 4;                 // wave's 16-row strip
    int rowq = wr + (quad << 2);     // this lane's 4 accumulator rows

    // ---- stage Q tile (fully coalesced: elems [tid*16, tid*16+16)) ----
    {
        int r = tid >> 2, c16 = (tid & 3) << 4;
        const bf16_t* Qb = Q + ((long)bh * 1024 + qt * 64) * 64;
        bf16x8 a = *(const bf16x8*)&Qb[r * 64 + c16];
        bf16x8 b = *(const bf16x8*)&Qb[r * 64 + c16 + 8];
        *(bf16x8*)&Qs[r * 72 + c16] = a;
        *(bf16x8*)&Qs[r * 72 + c16 + 8] = b;
    }

    float m_i[4] = {-1e30f, -1e30f, -1e30f, -1e30f};
    float l_i[4] = {0.f, 0.f, 0.f, 0.f};
    f32x4 o_acc[4];
    for (int j = 0; j < 4; j++) o_acc[j] = (f32x4){0.f, 0.f, 0.f, 0.f};

    int nt = causal ? (qt + 1) : (Sk >> 6);
    long kvbase = (long)bh * Sk * 64;

    for (int kt = 0; kt < nt; kt++) {
        __syncthreads();   // previous iter's Ks/Vt/Ps fully consumed
        {
            int r = tid >> 2, c16 = (tid & 3) << 4;
            long off = kvbase + (long)((kt << 6) + r) * 64 + c16;
            bf16x8 k0, k1, v0, v1;
            if (kv_f32) {
                const float* kp = (const float*)K + off;
                const float* vp = (const float*)V + off;
                k0 = load8f(kp); k1 = load8f(kp + 8);
                v0 = load8f(vp); v1 = load8f(vp + 8);
            } else {
                k0 = *(const bf16x8*)((const bf16_t*)K + off);
                k1 = *(const bf16x8*)((const bf16_t*)K + off + 8);
                v0 = *(const bf16x8*)((const bf16_t*)V + off);
                v1 = *(const bf16x8*)((const bf16_t*)V + off + 8);
            }
            *(bf16x8*)&Ks[r * 72 + c16] = k0;
            *(bf16x8*)&Ks[r * 72 + c16 + 8] = k1;
            for (int i = 0; i < 8; i++) {
                Vt[(c16 + i) * 72 + r]     = v0[i];
                Vt[(c16 + 8 + i) * 72 + r] = v1[i];
            }
        }
        __syncthreads();

        // ---- scores: S = (Q K^T) * 0.125 ----
        f32x4 s[4];
        for (int j = 0; j < 4; j++) s[j] = (f32x4){0.f, 0.f, 0.f, 0.f};
        for (int ks = 0; ks < 2; ks++) {
            int sl = (quad + (ks << 2)) << 3;
            bf16x8 aq = *(const bf16x8*)&Qs[(wr + l15) * 72 + sl];
            for (int j = 0; j < 4; j++) {
                bf16x8 bk = *(const bf16x8*)&Ks[((j << 4) + l15) * 72 + sl];
                s[j] = __builtin_amdgcn_mfma_f32_16x16x32_bf16(aq, bk, s[j], 0, 0, 0);
            }
        }

        // ---- online softmax (rows rowq..rowq+3, cols j*16+l15) ----
        int diag = causal && (kt == qt);
        for (int rr = 0; rr < 4; rr++) {
            float sv[4];
            for (int j = 0; j < 4; j++) {
                float x = s[j][rr] * 0.125f;
                if (diag && ((j << 4) + l15 > rowq + rr)) x = -1e30f;
                sv[j] = x;
            }
            float mx = fmaxf(fmaxf(sv[0], sv[1]), fmaxf(sv[2], sv[3]));
            for (int off = 1; off < 16; off <<= 1) mx = fmaxf(mx, __shfl_xor(mx, off));
            float mnew = fmaxf(m_i[rr], mx);
            float alpha = __expf(m_i[rr] - mnew);
            float p0 = __expf(sv[0] - mnew), p1 = __expf(sv[1] - mnew);
            float p2 = __expf(sv[2] - mnew), p3 = __expf(sv[3] - mnew);
            float rsum = p0 + p1 + p2 + p3;
            for (int off = 1; off < 16; off <<= 1) rsum += __shfl_xor(rsum, off);
            m_i[rr] = mnew;
            l_i[rr] = l_i[rr] * alpha + rsum;
            for (int j = 0; j < 4; j++) o_acc[j][rr] *= alpha;
            bf16_t* pr = &Ps[(rowq + rr) * 72 + l15];
            pr[0]  = (bf16_t)p0; pr[16] = (bf16_t)p1;
            pr[32] = (bf16_t)p2; pr[48] = (bf16_t)p3;
        }
        __syncthreads();

        // ---- O += P V  (A = Ps rows [own wave strip], B = Vt rows) ----
        for (int ks = 0; ks < 2; ks++) {
            int sl = (quad + (ks << 2)) << 3;
            bf16x8 ap = *(const bf16x8*)&Ps[(wr + l15) * 72 + sl];
            for (int j = 0; j < 4; j++) {
                bf16x8 bv = *(const bf16x8*)&Vt[((j << 4) + l15) * 72 + sl];
                o_acc[j] = __builtin_amdgcn_mfma_f32_16x16x32_bf16(ap, bv, o_acc[j], 0, 0, 0);
            }
        }
    }

    bf16_t* Ob = AO + ((long)bh * 1024 + qt * 64) * 64;
    for (int rr = 0; rr < 4; rr++) {
        float inv = 1.0f / l_i[rr];
        for (int j = 0; j < 4; j++)
            Ob[(rowq + rr) * 64 + (j << 4) + l15] = (bf16_t)(o_acc[j][rr] * inv);
    }
}

// ---------------------------------------------------------------------------
extern "C" void kernel_launch(void* const* d_in, const int* in_sizes, int n_in,
                              void* d_out, int out_size, void* d_ws, size_t ws_size,
                              hipStream_t stream)
{
    (void)in_sizes; (void)n_in; (void)out_size;
    const float* tgt       = (const float*)d_in[0];
    const float* mem       = (const float*)d_in[1];
    const float* Wq        = (const float*)d_in[2];
    const float* Wk        = (const float*)d_in[3];
    const float* Wv        = (const float*)d_in[4];
    const float* Wo        = (const float*)d_in[5];
    const float* mha_in_w  = (const float*)d_in[6];
    const float* mha_in_b  = (const float*)d_in[7];
    const float* mha_out_w = (const float*)d_in[8];
    const float* mha_out_b = (const float*)d_in[9];
    const float* W1        = (const float*)d_in[10];
    const float* b1        = (const float*)d_in[11];
    const float* W2        = (const float*)d_in[12];
    const float* b2        = (const float*)d_in[13];
    const float* g1        = (const float*)d_in[14];
    const float* be1       = (const float*)d_in[15];
    const float* g2        = (const float*)d_in[16];
    const float* be2       = (const float*)d_in[17];
    const float* g3        = (const float*)d_in[18];
    const float* be3       = (const float*)d_in[19];

    float* out_x = (float*)d_out;
    float* out_k = out_x + (1 << 22);
    float* out_v = out_k + (1 << 22);

    bf16_t* R0 = (bf16_t*)d_ws;
    bf16_t* R1 = R0 + (1 << 22);
    bf16_t* R2 = R1 + (1 << 22);

    dim3 blk(256);
    dim3 gA(16, 64);

    if (ws_size >= ((size_t)96 << 20)) {
        // ---------------- FAST PATH ----------------
        bf16_t* Hff  = R2 + (1 << 22);                              // [24,56) MB
        bf16_t* Wb   = (bf16_t*)((char*)d_ws + ((size_t)56 << 20)); // [56,88)
        bf16_t* memb = Wb + 16777216;                               // [88,96)
        // bf16 self-attn K/V copies live in the Hff region (free until FFN):
        bf16_t* saKb = Hff;                 // [24,32) MB
        bf16_t* saVb = Hff + (1 << 22);     // [32,40) MB
        const long WO_OFF  = 3145728;
        const long CQ_OFF  = 4194304;
        const long CKV_OFF = 5242880;
        const long CO_OFF  = 7340032;
        const long W1_OFF  = 8388608;
        const long W2_OFF  = 12582912;

        conv_kernel<<<10240, blk, 0, stream>>>(Wq, Wk, Wv, Wo, mha_in_w,
                                               mha_out_w, W1, W2, mem, Wb);

        // ---- self-attention ----
        ln_kernel<<<4096, blk, 0, stream>>>(tgt, g1, be1, R0);
        gemm_fast<4><<<dim3(24, 32), blk, 0, stream>>>(R0, 1024, 0, Wb, 0, 1024, 1024,
                                                       nullptr, 0, nullptr,
                                                       R1, out_k, out_v, 1, 3072, 0,
                                                       saKb, saVb);
        attn_kernel<<<gA, blk, 0, stream>>>(R1, saKb, saVb, R1, 1024, 1, 0);
        gemm_fast<2><<<dim3(16, 32), blk, 0, stream>>>(R1, 0, 1, Wb, WO_OFF, 1024, 1024,
                                                       nullptr, 0, tgt,
                                                       out_x, nullptr, nullptr, 0, 1024, 0,
                                                       nullptr, nullptr);

        // ---- cross-attention ----
        ln_kernel<<<4096, blk, 0, stream>>>(out_x, g2, be2, R0);
        gemm_fast<2><<<dim3(16, 32), blk, 0, stream>>>(R0, 1024, 0, Wb, CQ_OFF, 1024, 1024,
                                                       mha_in_b, 0, nullptr,
                                                       nullptr, nullptr, R1, 0, 1024, 0,
                                                       nullptr, nullptr);
        gemm_fast<4><<<dim3(16, 32), blk, 0, stream>>>(memb, 1024, 0, Wb, CKV_OFF, 1024, 1024,
                                                       mha_in_b, 1024, nullptr,
                                                       R2, R0, nullptr, 2, 2048, 0,
                                                       nullptr, nullptr);
        attn_kernel<<<gA, blk, 0, stream>>>(R1, R2, R0, R1, 1024, 0, 0);
        gemm_fast<2><<<dim3(16, 32), blk, 0, stream>>>(R1, 0, 1, Wb, CO_OFF, 1024, 1024,
                                                       mha_out_b, 0, out_x,
                                                       out_x, nullptr, nullptr, 0, 1024, 0,
                                                       nullptr, nullptr);

        // ---- FFN ----
        ln_kernel<<<4096, blk, 0, stream>>>(out_x, g3, be3, R0);
        gemm_fast<4><<<dim3(32, 32), blk, 0, stream>>>(R0, 1024, 0, Wb, W1_OFF, 1024, 1024,
                                                       b1, 0, nullptr,
                                                       nullptr, Hff, nullptr, 0, 4096, 1,
                                                       nullptr, nullptr);
        gemm_fast<2><<<dim3(16, 32), blk, 0, stream>>>(Hff, 4096, 0, Wb, W2_OFF, 4096, 4096,
                                                       b2, 0, out_x,
                                                       out_x, nullptr, nullptr, 0, 1024, 0,
                                                       nullptr, nullptr);
        return;
    }

    // ---------------- FALLBACK (round-5, known passing) ----------------
    dim3 gD(8, 32);
    dim3 gF1(32, 16);
    dim3 gF2(8, 16);

    ln_kernel<<<4096, blk, 0, stream>>>(tgt, g1, be1, R0);
    gemm_nt<<<gD, blk, 0, stream>>>(R0, 1024, 0, 0, Wq, 0, 1024, 1024,
                                    nullptr, 0, nullptr, nullptr, nullptr,
                                    nullptr, R1, 1024, 0);
    gemm_nt<<<gD, blk, 0, stream>>>(R0, 1024, 0, 0, Wk, 0, 1024, 1024,
                                    nullptr, 0, nullptr, nullptr, nullptr,
                                    out_k, nullptr, 1024, 0);
    gemm_nt<<<gD, blk, 0, stream>>>(R0, 1024, 0, 0, Wv, 0, 1024, 1024,
                                    nullptr, 0, nullptr, nullptr, nullptr,
                                    out_v, nullptr, 1024, 0);
    attn_kernel<<<gA, blk, 0, stream>>>(R1, out_k, out_v, R1, 1024, 1, 1);
    gemm_nt<<<gD, blk, 0, stream>>>(R1, 0, 1, 0, Wo, 0, 1024, 1024,
                                    nullptr, 0, tgt, out_x, nullptr,
                                    nullptr, nullptr, 1024, 0);

    ln_kernel<<<4096, blk, 0, stream>>>(out_x, g2, be2, R0);
    gemm_nt<<<gD, blk, 0, stream>>>(R0, 1024, 0, 0, mha_in_w, 0, 1024, 1024,
                                    mha_in_b, 0, nullptr, nullptr, nullptr,
                                    nullptr, R1, 1024, 0);
    gemm_nt<<<gD, blk, 0, stream>>>(mem, 1024, 0, 1, mha_in_w, (long)1 << 20, 1024, 1024,
                                    mha_in_b, 1024, nullptr, nullptr, nullptr,
                                    nullptr, R2, 1024, 0);
    gemm_nt<<<gD, blk, 0, stream>>>(mem, 1024, 0, 1, mha_in_w, (long)2 << 20, 1024, 1024,
                                    mha_in_b, 2048, nullptr, nullptr, nullptr,
                                    nullptr, R0, 1024, 0);
    attn_kernel<<<gA, blk, 0, stream>>>(R1, R2, R0, R1, 1024, 0, 0);
    gemm_nt<<<gD, blk, 0, stream>>>(R1, 0, 1, 0, mha_out_w, 0, 1024, 1024,
                                    mha_out_b, 0, out_x, out_x, nullptr,
                                    nullptr, nullptr, 1024, 0);

    ln_kernel<<<4096, blk, 0, stream>>>(out_x, g3, be3, R0);
    for (int c = 0; c < 2; c++) {
        const bf16_t* Ac = R0 + (long)c * 2048 * 1024;
        bf16_t*       Hc = R1;
        float*        Xc = out_x + (long)c * 2048 * 1024;
        gemm_nt<<<gF1, blk, 0, stream>>>(Ac, 1024, 0, 0, W1, 0, 1024, 1024,
                                         b1, 0, nullptr, nullptr, Hc,
                                         nullptr, nullptr, 4096, 1);
        gemm_nt<<<gF2, blk, 0, stream>>>(Hc, 4096, 0, 0, W2, 0, 4096, 4096,
                                         b2, 0, Xc, Xc, nullptr,
                                         nullptr, nullptr, 1024, 0);
    }
}

// Round 4
// 676.684 us; speedup vs baseline: 1.7997x; 1.2834x over previous
//
#include <hip/hip_runtime.h>

typedef __bf16 bf16_t;
typedef unsigned int u32;
typedef __attribute__((ext_vector_type(8))) __bf16 bf16x8;
typedef __attribute__((ext_vector_type(4))) __bf16 bf16x4;
typedef __attribute__((ext_vector_type(4))) float f32x4;

// B=4, S=SM=1024, D=1024, H=16, HD=64, DFF=4096; M = B*S = 4096 rows.
// Inputs fp32; d_out fp32 (x, sa_k, sa_v). Internals bf16 (MFMA).
// FAST PATH (ws >= 96MB): bf16 weights cached in ws.

__device__ __forceinline__ bf16x8 load8f(const float* f) {
    float4 a = *(const float4*)f;
    float4 b = *(const float4*)(f + 4);
    bf16x8 r;
    r[0] = (bf16_t)a.x; r[1] = (bf16_t)a.y; r[2] = (bf16_t)a.z; r[3] = (bf16_t)a.w;
    r[4] = (bf16_t)b.x; r[5] = (bf16_t)b.y; r[6] = (bf16_t)b.z; r[7] = (bf16_t)b.w;
    return r;
}

// async 16B/lane global->LDS; LDS dest = wave-uniform base + lane*16
__device__ __forceinline__ void gll16(const void* g, const void* l) {
    __builtin_amdgcn_global_load_lds(
        (const __attribute__((address_space(1))) u32*)(unsigned long long)g,
        (__attribute__((address_space(3))) u32*)(unsigned int)(unsigned long long)l,
        16, 0, 0);
}

// ---------------------------------------------------------------------------
// fp32 -> bf16 weight/mem conversion (one contiguous buffer).
// [0,1M) Wq | [1M,2M) Wk | [2M,3M) Wv | [3M,4M) Wo | [4M,7M) mha_in_w |
// [7M,8M) mha_out_w | [8M,12M) W1 | [12M,16M) W2 | [16M,20M) mem
// ---------------------------------------------------------------------------
__global__ __launch_bounds__(256) void conv_kernel(
    const float* __restrict__ Wq, const float* __restrict__ Wk,
    const float* __restrict__ Wv, const float* __restrict__ Wo,
    const float* __restrict__ Wio, const float* __restrict__ Woo,
    const float* __restrict__ W1, const float* __restrict__ W2,
    const float* __restrict__ mem, bf16_t* __restrict__ dst)
{
    long e = ((long)blockIdx.x * 256 + threadIdx.x) * 8;
    const float* s; long o;
    if      (e <  1048576) { s = Wq;  o = e; }
    else if (e <  2097152) { s = Wk;  o = e -  1048576; }
    else if (e <  3145728) { s = Wv;  o = e -  2097152; }
    else if (e <  4194304) { s = Wo;  o = e -  3145728; }
    else if (e <  7340032) { s = Wio; o = e -  4194304; }
    else if (e <  8388608) { s = Woo; o = e -  7340032; }
    else if (e < 12582912) { s = W1;  o = e -  8388608; }
    else if (e < 16777216) { s = W2;  o = e - 12582912; }
    else                   { s = mem; o = e - 16777216; }
    *(bf16x8*)&dst[e] = load8f(s + o);
}

// ---------------------------------------------------------------------------
// LayerNorm: one block per fp32 row of 1024 -> bf16 out (fp32 math).
// ---------------------------------------------------------------------------
__global__ __launch_bounds__(256) void ln_kernel(
    const float* __restrict__ x,
    const float* __restrict__ g, const float* __restrict__ be,
    bf16_t* __restrict__ out)
{
    int row = blockIdx.x, t = threadIdx.x;
    float4 q = *(const float4*)(x + (long)row * 1024 + t * 4);
    float v[4] = {q.x, q.y, q.z, q.w};
    float s = v[0] + v[1] + v[2] + v[3];
    float s2 = v[0]*v[0] + v[1]*v[1] + v[2]*v[2] + v[3]*v[3];
    for (int off = 32; off > 0; off >>= 1) {
        s  += __shfl_down(s, off);
        s2 += __shfl_down(s2, off);
    }
    __shared__ float rs[4], rq[4];
    int w = t >> 6;
    if ((t & 63) == 0) { rs[w] = s; rq[w] = s2; }
    __syncthreads();
    s  = rs[0] + rs[1] + rs[2] + rs[3];
    s2 = rq[0] + rq[1] + rq[2] + rq[3];
    float mean = s * (1.0f / 1024.0f);
    float var  = s2 * (1.0f / 1024.0f) - mean * mean;
    float rstd = rsqrtf(var + 1e-5f);
    int c = t * 4;
    for (int i = 0; i < 4; i++)
        out[(long)row * 1024 + c + i] =
            (bf16_t)((v[i] - mean) * rstd * g[c + i] + be[c + i]);
}

// ---------------------------------------------------------------------------
// BIG NT GEMM: 256x256 tile, 8 waves (512 thr), BK=64, 2 K-tile LDS buffers
// (128 KB). Pipeline: stage K-tile t+1 (8 gll16/wave, issued at phase 0 of
// tile t) into buf[p^1] while 4 phases of 16 MFMA consume buf[p]; raw
// s_barrier + vmcnt(0) ONLY at K-tile boundary — loads stay in flight
// across the whole tile (no per-phase drain). Same XOR chunk swizzle as
// gemm_fast (0 bank conflicts measured). Halves staged DMA bytes/FLOP vs
// 128x128 (r3 post-mortem: these GEMMs pin at ~5.9 TB/s of staged-DMA
// fabric traffic, so bytes/FLOP is the binding constraint).
// Wave w: wm=w>>2 (2 M-halves), wn=w&3 (4 N-quarters); per-wave C = 128x64.
// Epilogue modes identical to gemm_fast.
// ---------------------------------------------------------------------------
__global__ __launch_bounds__(512, 2) void gemm_big(
    const bf16_t* __restrict__ A, int lda,
    const bf16_t* __restrict__ Wb, long w_off, int ldw, int K,
    const float* __restrict__ bias, long b_off,
    const float* resid,
    void* o0, void* o1, void* o2, int mode, int N, int do_relu,
    void* o3, void* o4)
{
    __shared__ __align__(16) bf16_t As[2][256 * 64];
    __shared__ __align__(16) bf16_t Bs[2][256 * 64];
    int tid = threadIdx.x;
    int lin = blockIdx.y * gridDim.x + blockIdx.x;
    int mb = lin % gridDim.y, nb = lin / gridDim.y;  // m fastest -> XCD-local
    int m0 = mb << 8, n0 = nb << 8;
    int w = tid >> 6, lane = tid & 63;
    int l15 = lane & 15, quad = lane >> 4;
    int wm = w >> 2, wn = w & 3;
    int srow = lane >> 3;                 // row within 8-row staging group
    int cgo  = ((lane & 7) ^ srow) << 3;  // swizzled source chunk (elems)

    const bf16_t* Wg = Wb + w_off;
    int nk = K >> 6;

    f32x4 acc[8][4];
    #pragma unroll
    for (int i = 0; i < 8; i++)
        #pragma unroll
        for (int j = 0; j < 4; j++)
            acc[i][j] = (f32x4){0.f, 0.f, 0.f, 0.f};

    // stage one K-tile (256 rows A + 256 rows B) into buffer P at k-offset KK:
    // wave w stages row-groups {g*8+w : g=0..3} (8 rows each).
#define STAGEB(P, KK)                                                         \
    _Pragma("unroll")                                                         \
    for (int g = 0; g < 4; g++) {                                             \
        int rg = ((g << 3) + w) << 3;                                         \
        gll16(A  + (long)(m0 + rg + srow) * lda + (KK) + cgo, &As[P][rg << 6]); \
        gll16(Wg + (long)(n0 + rg + srow) * ldw + (KK) + cgo, &Bs[P][rg << 6]); \
    }

    STAGEB(0, 0)
    asm volatile("s_waitcnt vmcnt(0)");
    __builtin_amdgcn_s_barrier();
    __builtin_amdgcn_sched_barrier(0);

    for (int t = 0; t < nk; t++) {
        int p = t & 1;
        bf16x8 bfr[4][2];
        #pragma unroll
        for (int q = 0; q < 4; q++) {
            bf16x8 af[2][2];
            #pragma unroll
            for (int i2 = 0; i2 < 2; i2++)
                #pragma unroll
                for (int ks = 0; ks < 2; ks++) {
                    int row = (wm << 7) + (((q << 1) + i2) << 4) + l15;
                    int sl = ((quad + (ks << 2)) ^ (l15 & 7)) << 3;
                    af[i2][ks] = *(const bf16x8*)&As[p][(row << 6) + sl];
                }
            if (q == 0) {
                #pragma unroll
                for (int j = 0; j < 4; j++)
                    #pragma unroll
                    for (int ks = 0; ks < 2; ks++) {
                        int row = (wn << 6) + (j << 4) + l15;
                        int sl = ((quad + (ks << 2)) ^ (l15 & 7)) << 3;
                        bfr[j][ks] = *(const bf16x8*)&Bs[p][(row << 6) + sl];
                    }
                if (t + 1 < nk) STAGEB(p ^ 1, (t + 1) << 6)
            }
            asm volatile("s_waitcnt lgkmcnt(0)");
            __builtin_amdgcn_sched_barrier(0);
            __builtin_amdgcn_s_setprio(1);
            #pragma unroll
            for (int i2 = 0; i2 < 2; i2++)
                #pragma unroll
                for (int j = 0; j < 4; j++)
                    #pragma unroll
                    for (int ks = 0; ks < 2; ks++)
                        acc[(q << 1) + i2][j] = __builtin_amdgcn_mfma_f32_16x16x32_bf16(
                            af[i2][ks], bfr[j][ks], acc[(q << 1) + i2][j], 0, 0, 0);
            __builtin_amdgcn_s_setprio(0);
            __builtin_amdgcn_sched_barrier(0);
        }
        // K-tile boundary: own staging loads done, then all waves sync.
        if (t + 1 < nk) { asm volatile("s_waitcnt vmcnt(0)"); }
        __builtin_amdgcn_s_barrier();
        __builtin_amdgcn_sched_barrier(0);
    }
#undef STAGEB

    int rb = quad << 2;  // C/D: col = lane&15, row = quad*4 + reg
    for (int i = 0; i < 8; i++) {
        for (int j = 0; j < 4; j++) {
            int col = n0 + (wn << 6) + (j << 4) + l15;
            float bv = bias ? bias[b_off + col] : 0.0f;
            for (int r = 0; r < 4; r++) {
                int row = m0 + (wm << 7) + (i << 4) + rb + r;
                float v = acc[i][j][r] + bv;
                if (do_relu) v = fmaxf(v, 0.0f);
                if (mode == 0) {
                    long idx = (long)row * N + col;
                    if (resid) v += resid[idx];
                    if (o0) ((float*)o0)[idx] = v;
                    if (o1) ((bf16_t*)o1)[idx] = (bf16_t)v;
                    if (o2) {
                        long hidx = (((long)(row >> 10) * 16 + (col >> 6)) * 1024
                                     + (row & 1023)) * 64 + (col & 63);
                        ((bf16_t*)o2)[hidx] = (bf16_t)v;
                    }
                } else {
                    int seg = col >> 10, c = col & 1023;
                    long hidx = (((long)(row >> 10) * 16 + (c >> 6)) * 1024
                                 + (row & 1023)) * 64 + (c & 63);
                    if (mode == 1) {
                        if (seg == 0)      ((bf16_t*)o0)[hidx] = (bf16_t)v;
                        else if (seg == 1) {
                            ((float*)o1)[hidx] = v;
                            if (o3) ((bf16_t*)o3)[hidx] = (bf16_t)v;
                        } else {
                            ((float*)o2)[hidx] = v;
                            if (o4) ((bf16_t*)o4)[hidx] = (bf16_t)v;
                        }
                    } else {
                        if (seg == 0)      ((bf16_t*)o0)[hidx] = (bf16_t)v;
                        else               ((bf16_t*)o1)[hidx] = (bf16_t)v;
                    }
                }
            }
        }
    }
}

// ---------------------------------------------------------------------------
// FAST NT GEMM v4 (r3, proven): 128 x (NJ*32) tile, BK=64, double-buffered.
// Used for the N=1024 / small-grid GEMMs (WO, CQ, CO, W2).
// ---------------------------------------------------------------------------
template<int NJ>
__global__ __launch_bounds__(256) void gemm_fast(
    const bf16_t* __restrict__ A, int lda, int a_head,
    const bf16_t* __restrict__ Wb, long w_off, int ldw, int K,
    const float* __restrict__ bias, long b_off,
    const float* resid,
    void* o0, void* o1, void* o2, int mode, int N, int do_relu,
    void* o3, void* o4)
{
    constexpr int BN = NJ << 5;           // 128 or 64
    __shared__ __align__(16) bf16_t As[2][128 * 64];
    __shared__ __align__(16) bf16_t Bs[2][BN * 64];
    int tid = threadIdx.x;
    int lin = blockIdx.y * gridDim.x + blockIdx.x;   // HW dispatch order
    int mb = lin % gridDim.y, nb = lin / gridDim.y;  // m fastest -> A strip XCD-local
    int m0 = mb << 7, n0 = nb * BN;
    int w = tid >> 6, lane = tid & 63;
    int l15 = lane & 15, quad = lane >> 4;
    int wr = (w >> 1) << 6, wc = (w & 1) * (BN >> 1);

    int srow = lane >> 3;                 // row within 8-row staging group
    int cgo  = ((lane & 7) ^ srow) << 3;  // swizzled source chunk offset (elems)

    f32x4 acc[4][NJ];
    for (int i = 0; i < 4; i++)
        for (int j = 0; j < NJ; j++)
            acc[i][j] = (f32x4){0.f, 0.f, 0.f, 0.f};

    const bf16_t* Wg = Wb + w_off;
    int nk = K >> 6;

#define STAGE(P, KK)                                                          \
    {                                                                         \
        const bf16_t* Ab; long astr;                                          \
        if (a_head) {                                                         \
            int hh = (KK) >> 6;                                               \
            Ab = A + ((((long)(m0 >> 10)) * 16 + hh) * 1024 + (m0 & 1023)) * 64; \
            astr = 64;                                                        \
        } else {                                                              \
            Ab = A + (long)m0 * lda + (KK);                                   \
            astr = lda;                                                       \
        }                                                                     \
        const bf16_t* Bb = Wg + (long)n0 * ldw + (KK);                        \
        for (int t = 0; t < 4; t++) {                                         \
            int rb2 = (w << 5) + (t << 3);                                    \
            gll16(Ab + (long)(rb2 + srow) * astr + cgo, &As[P][rb2 << 6]);    \
        }                                                                     \
        for (int t = 0; t < NJ; t++) {                                        \
            int rb2 = w * (BN >> 2) + (t << 3);                               \
            gll16(Bb + (long)(rb2 + srow) * ldw + cgo, &Bs[P][rb2 << 6]);     \
        }                                                                     \
    }

#define COMPUTE(P)                                                            \
    for (int ks = 0; ks < 2; ks++) {                                          \
        bf16x8 af[4], bf_[NJ];                                                \
        int gA = quad + (ks << 2);                                            \
        int sl = (gA ^ (l15 & 7)) << 3;                                       \
        for (int i = 0; i < 4; i++)                                           \
            af[i]  = *(const bf16x8*)&As[P][((wr + (i << 4) + l15) << 6) + sl]; \
        for (int j = 0; j < NJ; j++)                                          \
            bf_[j] = *(const bf16x8*)&Bs[P][((wc + (j << 4) + l15) << 6) + sl]; \
        for (int i = 0; i < 4; i++)                                           \
            for (int j = 0; j < NJ; j++)                                      \
                acc[i][j] = __builtin_amdgcn_mfma_f32_16x16x32_bf16(          \
                    af[i], bf_[j], acc[i][j], 0, 0, 0);                       \
    }

    STAGE(0, 0)
    __syncthreads();
    int p = 0;
    for (int kt = 0; kt < nk; kt++) {
        if (kt + 1 < nk) STAGE(p ^ 1, (kt + 1) << 6)
        COMPUTE(p)
        __syncthreads();
        p ^= 1;
    }
#undef STAGE
#undef COMPUTE

    int rb = quad << 2;  // C/D: col = lane&15, row = quad*4 + reg
    for (int i = 0; i < 4; i++) {
        for (int j = 0; j < NJ; j++) {
            int col = n0 + wc + (j << 4) + l15;
            float bv = bias ? bias[b_off + col] : 0.0f;
            for (int r = 0; r < 4; r++) {
                int row = m0 + wr + (i << 4) + rb + r;
                float v = acc[i][j][r] + bv;
                if (do_relu) v = fmaxf(v, 0.0f);
                if (mode == 0) {
                    long idx = (long)row * N + col;
                    if (resid) v += resid[idx];
                    if (o0) ((float*)o0)[idx] = v;
                    if (o1) ((bf16_t*)o1)[idx] = (bf16_t)v;
                    if (o2) {
                        long hidx = (((long)(row >> 10) * 16 + (col >> 6)) * 1024
                                     + (row & 1023)) * 64 + (col & 63);
                        ((bf16_t*)o2)[hidx] = (bf16_t)v;
                    }
                } else {
                    int seg = col >> 10, c = col & 1023;
                    long hidx = (((long)(row >> 10) * 16 + (c >> 6)) * 1024
                                 + (row & 1023)) * 64 + (c & 63);
                    if (mode == 1) {
                        if (seg == 0)      ((bf16_t*)o0)[hidx] = (bf16_t)v;
                        else if (seg == 1) {
                            ((float*)o1)[hidx] = v;
                            if (o3) ((bf16_t*)o3)[hidx] = (bf16_t)v;
                        } else {
                            ((float*)o2)[hidx] = v;
                            if (o4) ((bf16_t*)o4)[hidx] = (bf16_t)v;
                        }
                    } else {
                        if (seg == 0)      ((bf16_t*)o0)[hidx] = (bf16_t)v;
                        else               ((bf16_t*)o1)[hidx] = (bf16_t)v;
                    }
                }
            }
        }
    }
}

// ---------------------------------------------------------------------------
// FALLBACK NT GEMM (round-5, fp32 weights) — only if ws < 96MB.
// ---------------------------------------------------------------------------
#define LDT 40

__global__ __launch_bounds__(256) void gemm_nt(
    const void* __restrict__ A, int lda, int a_head, int a_f32,
    const float* __restrict__ W, long w_off, int ldw,
    int K,
    const float* __restrict__ bias, long b_off,
    const float* __restrict__ resid,
    float*  out_f32, bf16_t* __restrict__ out_b16,
    float*  __restrict__ out_hf32, bf16_t* __restrict__ out_hb16,
    int N, int do_relu)
{
    __shared__ bf16_t As[128 * LDT];
    __shared__ bf16_t Bs[128 * LDT];
    int tid = threadIdx.x;
    int m0 = blockIdx.y << 7, n0 = blockIdx.x << 7;
    int wave = tid >> 6, lane = tid & 63;
    int wr = (wave >> 1) << 6;
    int wc = (wave & 1) << 6;
    int l15 = lane & 15, quad = lane >> 4;

    f32x4 acc[4][4];
    for (int i = 0; i < 4; i++)
        for (int j = 0; j < 4; j++)
            acc[i][j] = (f32x4){0.f, 0.f, 0.f, 0.f};

    int sr = tid >> 2;
    int sc = (tid & 3) << 3;

    for (int k0 = 0; k0 < K; k0 += 32) {
        int kk = k0 + sc;
        long ia0, ia1;
        if (a_head) {
            int hh = kk >> 6, dd = kk & 63;
            int r0g = m0 + sr, r1g = r0g + 64;
            ia0 = ((((long)(r0g >> 10) * 16 + hh) * 1024 + (r0g & 1023)) << 6) + dd;
            ia1 = ((((long)(r1g >> 10) * 16 + hh) * 1024 + (r1g & 1023)) << 6) + dd;
        } else {
            ia0 = (long)(m0 + sr) * lda + kk;
            ia1 = (long)(m0 + sr + 64) * lda + kk;
        }
        long iw0 = w_off + (long)(n0 + sr) * ldw + kk;
        long iw1 = w_off + (long)(n0 + sr + 64) * ldw + kk;
        __syncthreads();
        if (a_f32) {
            *(bf16x8*)&As[sr * LDT + sc]        = load8f((const float*)A + ia0);
            *(bf16x8*)&As[(sr + 64) * LDT + sc] = load8f((const float*)A + ia1);
        } else {
            *(bf16x8*)&As[sr * LDT + sc]        = *(const bf16x8*)((const bf16_t*)A + ia0);
            *(bf16x8*)&As[(sr + 64) * LDT + sc] = *(const bf16x8*)((const bf16_t*)A + ia1);
        }
        *(bf16x8*)&Bs[sr * LDT + sc]        = load8f(W + iw0);
        *(bf16x8*)&Bs[(sr + 64) * LDT + sc] = load8f(W + iw1);
        __syncthreads();
        bf16x8 afr[4], bfr[4];
        for (int i = 0; i < 4; i++)
            afr[i] = *(const bf16x8*)&As[(wr + i * 16 + l15) * LDT + quad * 8];
        for (int j = 0; j < 4; j++)
            bfr[j] = *(const bf16x8*)&Bs[(wc + j * 16 + l15) * LDT + quad * 8];
        for (int i = 0; i < 4; i++)
            for (int j = 0; j < 4; j++)
                acc[i][j] = __builtin_amdgcn_mfma_f32_16x16x32_bf16(
                    afr[i], bfr[j], acc[i][j], 0, 0, 0);
    }

    int rb = quad << 2;
    for (int i = 0; i < 4; i++) {
        for (int j = 0; j < 4; j++) {
            int col = n0 + wc + (j << 4) + l15;
            float bv = bias ? bias[b_off + col] : 0.0f;
            for (int r = 0; r < 4; r++) {
                int row = m0 + wr + (i << 4) + rb + r;
                float v = acc[i][j][r] + bv;
                if (do_relu) v = fmaxf(v, 0.0f);
                long idx = (long)row * N + col;
                if (resid) v += resid[idx];
                if (out_f32) out_f32[idx] = v;
                if (out_b16) out_b16[idx] = (bf16_t)v;
                if (out_hf32 || out_hb16) {
                    int bb = row >> 10, ss = row & 1023, hh = col >> 6, dd = col & 63;
                    long hidx = (((long)bb * 16 + hh) * 1024 + ss) * 64 + dd;
                    if (out_hf32) out_hf32[hidx] = v;
                    if (out_hb16) out_hb16[hidx] = (bf16_t)v;
                }
            }
        }
    }
}

// ---------------------------------------------------------------------------
// MFMA flash attention. Q bf16 head [B*H,S,64]; K/V head layout, bf16 or
// fp32 per kv_f32. Output bf16 in-place over Q.
// 4 waves/block; wave w owns Q rows [w*16, w*16+16) of a 64-row tile.
// Fragment layout mirrors gemm_fast (harness-verified): A row=l15,
// k-chunk=quad*8+ks*32; C/D row=quad*4+reg, col=l15.
// LDS tiles bf16 stride 72. V staged transposed so PV is NT like QK^T.
// Scale 1/sqrt(64) folded into f32 scores.
// ---------------------------------------------------------------------------
__global__ __launch_bounds__(256) void attn_kernel(
    const bf16_t* __restrict__ Q, const void* __restrict__ K,
    const void* __restrict__ V, bf16_t* __restrict__ AO,
    int Sk, int causal, int kv_f32)
{
    __shared__ __align__(16) bf16_t Qs[64 * 72];
    __shared__ __align__(16) bf16_t Ks[64 * 72];
    __shared__ __align__(16) bf16_t Vt[64 * 72];   // transposed: Vt[d][k]
    __shared__ __align__(16) bf16_t Ps[64 * 72];

    int tid = threadIdx.x;
    int qt = blockIdx.x, bh = blockIdx.y;
    int w = tid >> 6, lane = tid & 63;
    int l15 = lane & 15, quad = lane >> 4;
    int wr = w << 4;                 // wave's 16-row strip
    int rowq = wr + (quad << 2);     // this lane's 4 accumulator rows

    // ---- stage Q tile (fully coalesced: elems [tid*16, tid*16+16)) ----
    {
        int r = tid >> 2, c16 = (tid & 3) << 4;
        const bf16_t* Qb = Q + ((long)bh * 1024 + qt * 64) * 64;
        bf16x8 a = *(const bf16x8*)&Qb[r * 64 + c16];
        bf16x8 b = *(const bf16x8*)&Qb[r * 64 + c16 + 8];
        *(bf16x8*)&Qs[r * 72 + c16] = a;
        *(bf16x8*)&Qs[r * 72 + c16 + 8] = b;
    }

    float m_i[4] = {-1e30f, -1e30f, -1e30f, -1e30f};
    float l_i[4] = {0.f, 0.f, 0.f, 0.f};
    f32x4 o_acc[4];
    for (int j = 0; j < 4; j++) o_acc[j] = (f32x4){0.f, 0.f, 0.f, 0.f};

    int nt = causal ? (qt + 1) : (Sk >> 6);
    long kvbase = (long)bh * Sk * 64;

    for (int kt = 0; kt < nt; kt++) {
        __syncthreads();   // previous iter's Ks/Vt/Ps fully consumed
        {
            int r = tid >> 2, c16 = (tid & 3) << 4;
            long off = kvbase + (long)((kt << 6) + r) * 64 + c16;
            bf16x8 k0, k1, v0, v1;
            if (kv_f32) {
                const float* kp = (const float*)K + off;
                const float* vp = (const float*)V + off;
                k0 = load8f(kp); k1 = load8f(kp + 8);
                v0 = load8f(vp); v1 = load8f(vp + 8);
            } else {
                k0 = *(const bf16x8*)((const bf16_t*)K + off);
                k1 = *(const bf16x8*)((const bf16_t*)K + off + 8);
                v0 = *(const bf16x8*)((const bf16_t*)V + off);
                v1 = *(const bf16x8*)((const bf16_t*)V + off + 8);
            }
            *(bf16x8*)&Ks[r * 72 + c16] = k0;
            *(bf16x8*)&Ks[r * 72 + c16 + 8] = k1;
            for (int i = 0; i < 8; i++) {
                Vt[(c16 + i) * 72 + r]     = v0[i];
                Vt[(c16 + 8 + i) * 72 + r] = v1[i];
            }
        }
        __syncthreads();

        // ---- scores: S = (Q K^T) * 0.125 ----
        f32x4 s[4];
        for (int j = 0; j < 4; j++) s[j] = (f32x4){0.f, 0.f, 0.f, 0.f};
        for (int ks = 0; ks < 2; ks++) {
            int sl = (quad + (ks << 2)) << 3;
            bf16x8 aq = *(const bf16x8*)&Qs[(wr + l15) * 72 + sl];
            for (int j = 0; j < 4; j++) {
                bf16x8 bk = *(const bf16x8*)&Ks[((j << 4) + l15) * 72 + sl];
                s[j] = __builtin_amdgcn_mfma_f32_16x16x32_bf16(aq, bk, s[j], 0, 0, 0);
            }
        }

        // ---- online softmax (rows rowq..rowq+3, cols j*16+l15) ----
        int diag = causal && (kt == qt);
        for (int rr = 0; rr < 4; rr++) {
            float sv[4];
            for (int j = 0; j < 4; j++) {
                float x = s[j][rr] * 0.125f;
                if (diag && ((j << 4) + l15 > rowq + rr)) x = -1e30f;
                sv[j] = x;
            }
            float mx = fmaxf(fmaxf(sv[0], sv[1]), fmaxf(sv[2], sv[3]));
            for (int off = 1; off < 16; off <<= 1) mx = fmaxf(mx, __shfl_xor(mx, off));
            float mnew = fmaxf(m_i[rr], mx);
            float alpha = __expf(m_i[rr] - mnew);
            float p0 = __expf(sv[0] - mnew), p1 = __expf(sv[1] - mnew);
            float p2 = __expf(sv[2] - mnew), p3 = __expf(sv[3] - mnew);
            float rsum = p0 + p1 + p2 + p3;
            for (int off = 1; off < 16; off <<= 1) rsum += __shfl_xor(rsum, off);
            m_i[rr] = mnew;
            l_i[rr] = l_i[rr] * alpha + rsum;
            for (int j = 0; j < 4; j++) o_acc[j][rr] *= alpha;
            bf16_t* pr = &Ps[(rowq + rr) * 72 + l15];
            pr[0]  = (bf16_t)p0; pr[16] = (bf16_t)p1;
            pr[32] = (bf16_t)p2; pr[48] = (bf16_t)p3;
        }
        __syncthreads();

        // ---- O += P V  (A = Ps rows [own wave strip], B = Vt rows) ----
        for (int ks = 0; ks < 2; ks++) {
            int sl = (quad + (ks << 2)) << 3;
            bf16x8 ap = *(const bf16x8*)&Ps[(wr + l15) * 72 + sl];
            for (int j = 0; j < 4; j++) {
                bf16x8 bv = *(const bf16x8*)&Vt[((j << 4) + l15) * 72 + sl];
                o_acc[j] = __builtin_amdgcn_mfma_f32_16x16x32_bf16(ap, bv, o_acc[j], 0, 0, 0);
            }
        }
    }

    bf16_t* Ob = AO + ((long)bh * 1024 + qt * 64) * 64;
    for (int rr = 0; rr < 4; rr++) {
        float inv = 1.0f / l_i[rr];
        for (int j = 0; j < 4; j++)
            Ob[(rowq + rr) * 64 + (j << 4) + l15] = (bf16_t)(o_acc[j][rr] * inv);
    }
}

// ---------------------------------------------------------------------------
extern "C" void kernel_launch(void* const* d_in, const int* in_sizes, int n_in,
                              void* d_out, int out_size, void* d_ws, size_t ws_size,
                              hipStream_t stream)
{
    (void)in_sizes; (void)n_in; (void)out_size;
    const float* tgt       = (const float*)d_in[0];
    const float* mem       = (const float*)d_in[1];
    const float* Wq        = (const float*)d_in[2];
    const float* Wk        = (const float*)d_in[3];
    const float* Wv        = (const float*)d_in[4];
    const float* Wo        = (const float*)d_in[5];
    const float* mha_in_w  = (const float*)d_in[6];
    const float* mha_in_b  = (const float*)d_in[7];
    const float* mha_out_w = (const float*)d_in[8];
    const float* mha_out_b = (const float*)d_in[9];
    const float* W1        = (const float*)d_in[10];
    const float* b1        = (const float*)d_in[11];
    const float* W2        = (const float*)d_in[12];
    const float* b2        = (const float*)d_in[13];
    const float* g1        = (const float*)d_in[14];
    const float* be1       = (const float*)d_in[15];
    const float* g2        = (const float*)d_in[16];
    const float* be2       = (const float*)d_in[17];
    const float* g3        = (const float*)d_in[18];
    const float* be3       = (const float*)d_in[19];

    float* out_x = (float*)d_out;
    float* out_k = out_x + (1 << 22);
    float* out_v = out_k + (1 << 22);

    bf16_t* R0 = (bf16_t*)d_ws;
    bf16_t* R1 = R0 + (1 << 22);
    bf16_t* R2 = R1 + (1 << 22);

    dim3 blk(256);
    dim3 blk5(512);
    dim3 gA(16, 64);

    if (ws_size >= ((size_t)96 << 20)) {
        // ---------------- FAST PATH ----------------
        bf16_t* Hff  = R2 + (1 << 22);                              // [24,56) MB
        bf16_t* Wb   = (bf16_t*)((char*)d_ws + ((size_t)56 << 20)); // [56,88)
        bf16_t* memb = Wb + 16777216;                               // [88,96)
        // bf16 self-attn K/V copies live in the Hff region (free until FFN):
        bf16_t* saKb = Hff;                 // [24,32) MB
        bf16_t* saVb = Hff + (1 << 22);     // [32,40) MB
        const long WO_OFF  = 3145728;
        const long CQ_OFF  = 4194304;
        const long CKV_OFF = 5242880;
        const long CO_OFF  = 7340032;
        const long W1_OFF  = 8388608;
        const long W2_OFF  = 12582912;

        conv_kernel<<<10240, blk, 0, stream>>>(Wq, Wk, Wv, Wo, mha_in_w,
                                               mha_out_w, W1, W2, mem, Wb);

        // ---- self-attention ----
        ln_kernel<<<4096, blk, 0, stream>>>(tgt, g1, be1, R0);
        gemm_big<<<dim3(12, 16), blk5, 0, stream>>>(R0, 1024, Wb, 0, 1024, 1024,
                                                    nullptr, 0, nullptr,
                                                    R1, out_k, out_v, 1, 3072, 0,
                                                    saKb, saVb);
        attn_kernel<<<gA, blk, 0, stream>>>(R1, saKb, saVb, R1, 1024, 1, 0);
        gemm_fast<2><<<dim3(16, 32), blk, 0, stream>>>(R1, 0, 1, Wb, WO_OFF, 1024, 1024,
                                                       nullptr, 0, tgt,
                                                       out_x, nullptr, nullptr, 0, 1024, 0,
                                                       nullptr, nullptr);

        // ---- cross-attention ----
        ln_kernel<<<4096, blk, 0, stream>>>(out_x, g2, be2, R0);
        gemm_fast<2><<<dim3(16, 32), blk, 0, stream>>>(R0, 1024, 0, Wb, CQ_OFF, 1024, 1024,
                                                       mha_in_b, 0, nullptr,
                                                       nullptr, nullptr, R1, 0, 1024, 0,
                                                       nullptr, nullptr);
        gemm_big<<<dim3(8, 16), blk5, 0, stream>>>(memb, 1024, Wb, CKV_OFF, 1024, 1024,
                                                   mha_in_b, 1024, nullptr,
                                                   R2, R0, nullptr, 2, 2048, 0,
                                                   nullptr, nullptr);
        attn_kernel<<<gA, blk, 0, stream>>>(R1, R2, R0, R1, 1024, 0, 0);
        gemm_fast<2><<<dim3(16, 32), blk, 0, stream>>>(R1, 0, 1, Wb, CO_OFF, 1024, 1024,
                                                       mha_out_b, 0, out_x,
                                                       out_x, nullptr, nullptr, 0, 1024, 0,
                                                       nullptr, nullptr);

        // ---- FFN ----
        ln_kernel<<<4096, blk, 0, stream>>>(out_x, g3, be3, R0);
        gemm_big<<<dim3(16, 16), blk5, 0, stream>>>(R0, 1024, Wb, W1_OFF, 1024, 1024,
                                                    b1, 0, nullptr,
                                                    nullptr, Hff, nullptr, 0, 4096, 1,
                                                    nullptr, nullptr);
        gemm_fast<2><<<dim3(16, 32), blk, 0, stream>>>(Hff, 4096, 0, Wb, W2_OFF, 4096, 4096,
                                                       b2, 0, out_x,
                                                       out_x, nullptr, nullptr, 0, 1024, 0,
                                                       nullptr, nullptr);
        return;
    }

    // ---------------- FALLBACK (round-5, known passing) ----------------
    dim3 gD(8, 32);
    dim3 gF1(32, 16);
    dim3 gF2(8, 16);

    ln_kernel<<<4096, blk, 0, stream>>>(tgt, g1, be1, R0);
    gemm_nt<<<gD, blk, 0, stream>>>(R0, 1024, 0, 0, Wq, 0, 1024, 1024,
                                    nullptr, 0, nullptr, nullptr, nullptr,
                                    nullptr, R1, 1024, 0);
    gemm_nt<<<gD, blk, 0, stream>>>(R0, 1024, 0, 0, Wk, 0, 1024, 1024,
                                    nullptr, 0, nullptr, nullptr, nullptr,
                                    out_k, nullptr, 1024, 0);
    gemm_nt<<<gD, blk, 0, stream>>>(R0, 1024, 0, 0, Wv, 0, 1024, 1024,
                                    nullptr, 0, nullptr, nullptr, nullptr,
                                    out_v, nullptr, 1024, 0);
    attn_kernel<<<gA, blk, 0, stream>>>(R1, out_k, out_v, R1, 1024, 1, 1);
    gemm_nt<<<gD, blk, 0, stream>>>(R1, 0, 1, 0, Wo, 0, 1024, 1024,
                                    nullptr, 0, tgt, out_x, nullptr,
                                    nullptr, nullptr, 1024, 0);

    ln_kernel<<<4096, blk, 0, stream>>>(out_x, g2, be2, R0);
    gemm_nt<<<gD, blk, 0, stream>>>(R0, 1024, 0, 0, mha_in_w, 0, 1024, 1024,
                                    mha_in_b, 0, nullptr, nullptr, nullptr,
                                    nullptr, R1, 1024, 0);
    gemm_nt<<<gD, blk, 0, stream>>>(mem, 1024, 0, 1, mha_in_w, (long)1 << 20, 1024, 1024,
                                    mha_in_b, 1024, nullptr, nullptr, nullptr,
                                    nullptr, R2, 1024, 0);
    gemm_nt<<<gD, blk, 0, stream>>>(mem, 1024, 0, 1, mha_in_w, (long)2 << 20, 1024, 1024,
                                    mha_in_b, 2048, nullptr, nullptr, nullptr,
                                    nullptr, R0, 1024, 0);
    attn_kernel<<<gA, blk, 0, stream>>>(R1, R2, R0, R1, 1024, 0, 0);
    gemm_nt<<<gD, blk, 0, stream>>>(R1, 0, 1, 0, mha_out_w, 0, 1024, 1024,
                                    mha_out_b, 0, out_x, out_x, nullptr,
                                    nullptr, nullptr, 1024, 0);

    ln_kernel<<<4096, blk, 0, stream>>>(out_x, g3, be3, R0);
    for (int c = 0; c < 2; c++) {
        const bf16_t* Ac = R0 + (long)c * 2048 * 1024;
        bf16_t*       Hc = R1;
        float*        Xc = out_x + (long)c * 2048 * 1024;
        gemm_nt<<<gF1, blk, 0, stream>>>(Ac, 1024, 0, 0, W1, 0, 1024, 1024,
                                         b1, 0, nullptr, nullptr, Hc,
                                         nullptr, nullptr, 4096, 1);
        gemm_nt<<<gF2, blk, 0, stream>>>(Hc, 4096, 0, 0, W2, 0, 4096, 4096,
                                         b2, 0, Xc, Xc, nullptr,
                                         nullptr, nullptr, 1024, 0);
    }
}

// Round 5
// 623.407 us; speedup vs baseline: 1.9535x; 1.0855x over previous
//
#include <hip/hip_runtime.h>

typedef __bf16 bf16_t;
typedef unsigned int u32;
typedef __attribute__((ext_vector_type(8))) __bf16 bf16x8;
typedef __attribute__((ext_vector_type(4))) __bf16 bf16x4;
typedef __attribute__((ext_vector_type(4))) float f32x4;

// B=4, S=SM=1024, D=1024, H=16, HD=64, DFF=4096; M = B*S = 4096 rows.
// Inputs fp32; d_out fp32 (x, sa_k, sa_v). Internals bf16 (MFMA).
// FAST PATH (ws >= 96MB): bf16 weights cached in ws.

__device__ __forceinline__ bf16x8 load8f(const float* f) {
    float4 a = *(const float4*)f;
    float4 b = *(const float4*)(f + 4);
    bf16x8 r;
    r[0] = (bf16_t)a.x; r[1] = (bf16_t)a.y; r[2] = (bf16_t)a.z; r[3] = (bf16_t)a.w;
    r[4] = (bf16_t)b.x; r[5] = (bf16_t)b.y; r[6] = (bf16_t)b.z; r[7] = (bf16_t)b.w;
    return r;
}

// async 16B/lane global->LDS; LDS dest = wave-uniform base + lane*16
__device__ __forceinline__ void gll16(const void* g, const void* l) {
    __builtin_amdgcn_global_load_lds(
        (const __attribute__((address_space(1))) u32*)(unsigned long long)g,
        (__attribute__((address_space(3))) u32*)(unsigned int)(unsigned long long)l,
        16, 0, 0);
}

// ---------------------------------------------------------------------------
// fp32 -> bf16 weight/mem conversion (one contiguous buffer).
// ---------------------------------------------------------------------------
__global__ __launch_bounds__(256) void conv_kernel(
    const float* __restrict__ Wq, const float* __restrict__ Wk,
    const float* __restrict__ Wv, const float* __restrict__ Wo,
    const float* __restrict__ Wio, const float* __restrict__ Woo,
    const float* __restrict__ W1, const float* __restrict__ W2,
    const float* __restrict__ mem, bf16_t* __restrict__ dst)
{
    long e = ((long)blockIdx.x * 256 + threadIdx.x) * 8;
    const float* s; long o;
    if      (e <  1048576) { s = Wq;  o = e; }
    else if (e <  2097152) { s = Wk;  o = e -  1048576; }
    else if (e <  3145728) { s = Wv;  o = e -  2097152; }
    else if (e <  4194304) { s = Wo;  o = e -  3145728; }
    else if (e <  7340032) { s = Wio; o = e -  4194304; }
    else if (e <  8388608) { s = Woo; o = e -  7340032; }
    else if (e < 12582912) { s = W1;  o = e -  8388608; }
    else if (e < 16777216) { s = W2;  o = e - 12582912; }
    else                   { s = mem; o = e - 16777216; }
    *(bf16x8*)&dst[e] = load8f(s + o);
}

// ---------------------------------------------------------------------------
// LayerNorm: one block per fp32 row of 1024 -> bf16 out (fp32 math).
// ---------------------------------------------------------------------------
__global__ __launch_bounds__(256) void ln_kernel(
    const float* __restrict__ x,
    const float* __restrict__ g, const float* __restrict__ be,
    bf16_t* __restrict__ out)
{
    int row = blockIdx.x, t = threadIdx.x;
    float4 q = *(const float4*)(x + (long)row * 1024 + t * 4);
    float v[4] = {q.x, q.y, q.z, q.w};
    float s = v[0] + v[1] + v[2] + v[3];
    float s2 = v[0]*v[0] + v[1]*v[1] + v[2]*v[2] + v[3]*v[3];
    for (int off = 32; off > 0; off >>= 1) {
        s  += __shfl_down(s, off);
        s2 += __shfl_down(s2, off);
    }
    __shared__ float rs[4], rq[4];
    int w = t >> 6;
    if ((t & 63) == 0) { rs[w] = s; rq[w] = s2; }
    __syncthreads();
    s  = rs[0] + rs[1] + rs[2] + rs[3];
    s2 = rq[0] + rq[1] + rq[2] + rq[3];
    float mean = s * (1.0f / 1024.0f);
    float var  = s2 * (1.0f / 1024.0f) - mean * mean;
    float rstd = rsqrtf(var + 1e-5f);
    int c = t * 4;
    for (int i = 0; i < 4; i++)
        out[(long)row * 1024 + c + i] =
            (bf16_t)((v[i] - mean) * rstd * g[c + i] + be[c + i]);
}

// ---------------------------------------------------------------------------
// BIG NT GEMM, templated M-tile: (MI*32) x 256 tile, 8 waves, BK=64,
// 2 K-tile LDS buffers. MI=8: 256x256 (128KB LDS, QKV/W1). MI=4: 128x256
// (96KB LDS, CKV -> grid (8,32)=256 blocks = full machine; r4: (8,16)=128
// blocks left half the CUs idle).
// Pipeline: stage K-tile t+1 at phase 0 of tile t into buf[p^1]; raw
// s_barrier + vmcnt(0) only at K-tile boundary. XOR chunk swizzle (0 bank
// conflicts measured).
// Wave w: wm=w>>2 (2 M-halves), wn=w&3 (4 N-quarters).
// mode 0: o0=f32 rm | o1=b16 rm | o2=b16 head
// mode 1 (QKV): seg0->o0 b16 head; seg1->o1 f32 head (+o3 b16 head);
//               seg2->o2 f32 head (+o4 b16 V-TRANSPOSED [BH][64][S])
// mode 2 (crossKV): seg0->o0 b16 head, seg1->o1 b16 V-TRANSPOSED
// ---------------------------------------------------------------------------
template<int MI>
__global__ __launch_bounds__(512, 2) void gemm_big(
    const bf16_t* __restrict__ A, int lda,
    const bf16_t* __restrict__ Wb, long w_off, int ldw, int K,
    const float* __restrict__ bias, long b_off,
    const float* resid,
    void* o0, void* o1, void* o2, int mode, int N, int do_relu,
    void* o3, void* o4)
{
    constexpr int BM = MI << 5;
    __shared__ __align__(16) bf16_t As[2][BM * 64];
    __shared__ __align__(16) bf16_t Bs[2][256 * 64];
    int tid = threadIdx.x;
    int lin = blockIdx.y * gridDim.x + blockIdx.x;
    int mb = lin % gridDim.y, nb = lin / gridDim.y;  // m fastest -> XCD-local
    int m0 = mb * BM, n0 = nb << 8;
    int w = tid >> 6, lane = tid & 63;
    int l15 = lane & 15, quad = lane >> 4;
    int wm = w >> 2, wn = w & 3;
    int srow = lane >> 3;                 // row within 8-row staging group
    int cgo  = ((lane & 7) ^ srow) << 3;  // swizzled source chunk (elems)

    const bf16_t* Wg = Wb + w_off;
    int nk = K >> 6;

    f32x4 acc[MI][4];
    #pragma unroll
    for (int i = 0; i < MI; i++)
        #pragma unroll
        for (int j = 0; j < 4; j++)
            acc[i][j] = (f32x4){0.f, 0.f, 0.f, 0.f};

#define STAGEB(P, KK)                                                         \
    _Pragma("unroll")                                                         \
    for (int g = 0; g < (MI >> 1); g++) {                                     \
        int rg = ((g << 3) + w) << 3;                                         \
        gll16(A  + (long)(m0 + rg + srow) * lda + (KK) + cgo, &As[P][rg << 6]); \
    }                                                                         \
    _Pragma("unroll")                                                         \
    for (int g = 0; g < 4; g++) {                                             \
        int rg = ((g << 3) + w) << 3;                                         \
        gll16(Wg + (long)(n0 + rg + srow) * ldw + (KK) + cgo, &Bs[P][rg << 6]); \
    }

    STAGEB(0, 0)
    asm volatile("s_waitcnt vmcnt(0)");
    __builtin_amdgcn_s_barrier();
    __builtin_amdgcn_sched_barrier(0);

    for (int t = 0; t < nk; t++) {
        int p = t & 1;
        bf16x8 bfr[4][2];
        #pragma unroll
        for (int q = 0; q < (MI >> 1); q++) {
            bf16x8 af[2][2];
            #pragma unroll
            for (int i2 = 0; i2 < 2; i2++)
                #pragma unroll
                for (int ks = 0; ks < 2; ks++) {
                    int row = wm * (MI << 4) + (((q << 1) + i2) << 4) + l15;
                    int sl = ((quad + (ks << 2)) ^ (l15 & 7)) << 3;
                    af[i2][ks] = *(const bf16x8*)&As[p][(row << 6) + sl];
                }
            if (q == 0) {
                #pragma unroll
                for (int j = 0; j < 4; j++)
                    #pragma unroll
                    for (int ks = 0; ks < 2; ks++) {
                        int row = (wn << 6) + (j << 4) + l15;
                        int sl = ((quad + (ks << 2)) ^ (l15 & 7)) << 3;
                        bfr[j][ks] = *(const bf16x8*)&Bs[p][(row << 6) + sl];
                    }
                if (t + 1 < nk) STAGEB(p ^ 1, (t + 1) << 6)
            }
            asm volatile("s_waitcnt lgkmcnt(0)");
            __builtin_amdgcn_sched_barrier(0);
            __builtin_amdgcn_s_setprio(1);
            #pragma unroll
            for (int i2 = 0; i2 < 2; i2++)
                #pragma unroll
                for (int j = 0; j < 4; j++)
                    #pragma unroll
                    for (int ks = 0; ks < 2; ks++)
                        acc[(q << 1) + i2][j] = __builtin_amdgcn_mfma_f32_16x16x32_bf16(
                            af[i2][ks], bfr[j][ks], acc[(q << 1) + i2][j], 0, 0, 0);
            __builtin_amdgcn_s_setprio(0);
            __builtin_amdgcn_sched_barrier(0);
        }
        if (t + 1 < nk) { asm volatile("s_waitcnt vmcnt(0)"); }
        __builtin_amdgcn_s_barrier();
        __builtin_amdgcn_sched_barrier(0);
    }
#undef STAGEB

    int rb = quad << 2;  // C/D: col = lane&15, row = quad*4 + reg
    for (int i = 0; i < MI; i++) {
        for (int j = 0; j < 4; j++) {
            int col = n0 + (wn << 6) + (j << 4) + l15;
            float bv = bias ? bias[b_off + col] : 0.0f;
            int row0 = m0 + wm * (MI << 4) + (i << 4) + rb;
            float vv[4];
            for (int r = 0; r < 4; r++) {
                float v = acc[i][j][r] + bv;
                if (do_relu) v = fmaxf(v, 0.0f);
                vv[r] = v;
            }
            if (mode == 0) {
                for (int r = 0; r < 4; r++) {
                    int row = row0 + r;
                    long idx = (long)row * N + col;
                    float v = vv[r];
                    if (resid) v += resid[idx];
                    if (o0) ((float*)o0)[idx] = v;
                    if (o1) ((bf16_t*)o1)[idx] = (bf16_t)v;
                    if (o2) {
                        long hidx = (((long)(row >> 10) * 16 + (col >> 6)) * 1024
                                     + (row & 1023)) * 64 + (col & 63);
                        ((bf16_t*)o2)[hidx] = (bf16_t)v;
                    }
                }
            } else {
                int seg = col >> 10, c = col & 1023;
                long hb = (long)(row0 >> 10) * 16 + (c >> 6);
                long hidx0 = (hb * 1024 + (row0 & 1023)) * 64 + (c & 63);
                if (mode == 1) {
                    if (seg == 0) {
                        for (int r = 0; r < 4; r++)
                            ((bf16_t*)o0)[hidx0 + r * 64] = (bf16_t)vv[r];
                    } else if (seg == 1) {
                        for (int r = 0; r < 4; r++) {
                            ((float*)o1)[hidx0 + r * 64] = vv[r];
                            if (o3) ((bf16_t*)o3)[hidx0 + r * 64] = (bf16_t)vv[r];
                        }
                    } else {
                        for (int r = 0; r < 4; r++)
                            ((float*)o2)[hidx0 + r * 64] = vv[r];
                        if (o4) {
                            long vt0 = (hb * 64 + (c & 63)) * 1024 + (row0 & 1023);
                            bf16x4 pk;
                            for (int r = 0; r < 4; r++) pk[r] = (bf16_t)vv[r];
                            *(bf16x4*)&((bf16_t*)o4)[vt0] = pk;
                        }
                    }
                } else {
                    if (seg == 0) {
                        for (int r = 0; r < 4; r++)
                            ((bf16_t*)o0)[hidx0 + r * 64] = (bf16_t)vv[r];
                    } else {
                        long vt0 = (hb * 64 + (c & 63)) * 1024 + (row0 & 1023);
                        bf16x4 pk;
                        for (int r = 0; r < 4; r++) pk[r] = (bf16_t)vv[r];
                        *(bf16x4*)&((bf16_t*)o1)[vt0] = pk;
                    }
                }
            }
        }
    }
}

// ---------------------------------------------------------------------------
// FAST NT GEMM v4 (r3, proven): 128 x (NJ*32) tile, BK=64, double-buffered.
// Used for the N=1024 / small-grid GEMMs (WO, CQ, CO, W2).
// ---------------------------------------------------------------------------
template<int NJ>
__global__ __launch_bounds__(256) void gemm_fast(
    const bf16_t* __restrict__ A, int lda, int a_head,
    const bf16_t* __restrict__ Wb, long w_off, int ldw, int K,
    const float* __restrict__ bias, long b_off,
    const float* resid,
    void* o0, void* o1, void* o2, int mode, int N, int do_relu,
    void* o3, void* o4)
{
    constexpr int BN = NJ << 5;           // 128 or 64
    __shared__ __align__(16) bf16_t As[2][128 * 64];
    __shared__ __align__(16) bf16_t Bs[2][BN * 64];
    int tid = threadIdx.x;
    int lin = blockIdx.y * gridDim.x + blockIdx.x;   // HW dispatch order
    int mb = lin % gridDim.y, nb = lin / gridDim.y;  // m fastest -> A strip XCD-local
    int m0 = mb << 7, n0 = nb * BN;
    int w = tid >> 6, lane = tid & 63;
    int l15 = lane & 15, quad = lane >> 4;
    int wr = (w >> 1) << 6, wc = (w & 1) * (BN >> 1);

    int srow = lane >> 3;                 // row within 8-row staging group
    int cgo  = ((lane & 7) ^ srow) << 3;  // swizzled source chunk offset (elems)

    f32x4 acc[4][NJ];
    for (int i = 0; i < 4; i++)
        for (int j = 0; j < NJ; j++)
            acc[i][j] = (f32x4){0.f, 0.f, 0.f, 0.f};

    const bf16_t* Wg = Wb + w_off;
    int nk = K >> 6;

#define STAGE(P, KK)                                                          \
    {                                                                         \
        const bf16_t* Ab; long astr;                                          \
        if (a_head) {                                                         \
            int hh = (KK) >> 6;                                               \
            Ab = A + ((((long)(m0 >> 10)) * 16 + hh) * 1024 + (m0 & 1023)) * 64; \
            astr = 64;                                                        \
        } else {                                                              \
            Ab = A + (long)m0 * lda + (KK);                                   \
            astr = lda;                                                       \
        }                                                                     \
        const bf16_t* Bb = Wg + (long)n0 * ldw + (KK);                        \
        for (int t = 0; t < 4; t++) {                                         \
            int rb2 = (w << 5) + (t << 3);                                    \
            gll16(Ab + (long)(rb2 + srow) * astr + cgo, &As[P][rb2 << 6]);    \
        }                                                                     \
        for (int t = 0; t < NJ; t++) {                                        \
            int rb2 = w * (BN >> 2) + (t << 3);                               \
            gll16(Bb + (long)(rb2 + srow) * ldw + cgo, &Bs[P][rb2 << 6]);     \
        }                                                                     \
    }

#define COMPUTE(P)                                                            \
    for (int ks = 0; ks < 2; ks++) {                                          \
        bf16x8 af[4], bf_[NJ];                                                \
        int gA = quad + (ks << 2);                                            \
        int sl = (gA ^ (l15 & 7)) << 3;                                       \
        for (int i = 0; i < 4; i++)                                           \
            af[i]  = *(const bf16x8*)&As[P][((wr + (i << 4) + l15) << 6) + sl]; \
        for (int j = 0; j < NJ; j++)                                          \
            bf_[j] = *(const bf16x8*)&Bs[P][((wc + (j << 4) + l15) << 6) + sl]; \
        for (int i = 0; i < 4; i++)                                           \
            for (int j = 0; j < NJ; j++)                                      \
                acc[i][j] = __builtin_amdgcn_mfma_f32_16x16x32_bf16(          \
                    af[i], bf_[j], acc[i][j], 0, 0, 0);                       \
    }

    STAGE(0, 0)
    __syncthreads();
    int p = 0;
    for (int kt = 0; kt < nk; kt++) {
        if (kt + 1 < nk) STAGE(p ^ 1, (kt + 1) << 6)
        COMPUTE(p)
        __syncthreads();
        p ^= 1;
    }
#undef STAGE
#undef COMPUTE

    int rb = quad << 2;  // C/D: col = lane&15, row = quad*4 + reg
    for (int i = 0; i < 4; i++) {
        for (int j = 0; j < NJ; j++) {
            int col = n0 + wc + (j << 4) + l15;
            float bv = bias ? bias[b_off + col] : 0.0f;
            for (int r = 0; r < 4; r++) {
                int row = m0 + wr + (i << 4) + rb + r;
                float v = acc[i][j][r] + bv;
                if (do_relu) v = fmaxf(v, 0.0f);
                if (mode == 0) {
                    long idx = (long)row * N + col;
                    if (resid) v += resid[idx];
                    if (o0) ((float*)o0)[idx] = v;
                    if (o1) ((bf16_t*)o1)[idx] = (bf16_t)v;
                    if (o2) {
                        long hidx = (((long)(row >> 10) * 16 + (col >> 6)) * 1024
                                     + (row & 1023)) * 64 + (col & 63);
                        ((bf16_t*)o2)[hidx] = (bf16_t)v;
                    }
                } else {
                    int seg = col >> 10, c = col & 1023;
                    long hidx = (((long)(row >> 10) * 16 + (c >> 6)) * 1024
                                 + (row & 1023)) * 64 + (c & 63);
                    if (mode == 1) {
                        if (seg == 0)      ((bf16_t*)o0)[hidx] = (bf16_t)v;
                        else if (seg == 1) {
                            ((float*)o1)[hidx] = v;
                            if (o3) ((bf16_t*)o3)[hidx] = (bf16_t)v;
                        } else {
                            ((float*)o2)[hidx] = v;
                            if (o4) ((bf16_t*)o4)[hidx] = (bf16_t)v;
                        }
                    } else {
                        if (seg == 0)      ((bf16_t*)o0)[hidx] = (bf16_t)v;
                        else               ((bf16_t*)o1)[hidx] = (bf16_t)v;
                    }
                }
            }
        }
    }
}

// ---------------------------------------------------------------------------
// FALLBACK NT GEMM (round-5, fp32 weights) — only if ws < 96MB.
// ---------------------------------------------------------------------------
#define LDT 40

__global__ __launch_bounds__(256) void gemm_nt(
    const void* __restrict__ A, int lda, int a_head, int a_f32,
    const float* __restrict__ W, long w_off, int ldw,
    int K,
    const float* __restrict__ bias, long b_off,
    const float* __restrict__ resid,
    float*  out_f32, bf16_t* __restrict__ out_b16,
    float*  __restrict__ out_hf32, bf16_t* __restrict__ out_hb16,
    int N, int do_relu)
{
    __shared__ bf16_t As[128 * LDT];
    __shared__ bf16_t Bs[128 * LDT];
    int tid = threadIdx.x;
    int m0 = blockIdx.y << 7, n0 = blockIdx.x << 7;
    int wave = tid >> 6, lane = tid & 63;
    int wr = (wave >> 1) << 6;
    int wc = (wave & 1) << 6;
    int l15 = lane & 15, quad = lane >> 4;

    f32x4 acc[4][4];
    for (int i = 0; i < 4; i++)
        for (int j = 0; j < 4; j++)
            acc[i][j] = (f32x4){0.f, 0.f, 0.f, 0.f};

    int sr = tid >> 2;
    int sc = (tid & 3) << 3;

    for (int k0 = 0; k0 < K; k0 += 32) {
        int kk = k0 + sc;
        long ia0, ia1;
        if (a_head) {
            int hh = kk >> 6, dd = kk & 63;
            int r0g = m0 + sr, r1g = r0g + 64;
            ia0 = ((((long)(r0g >> 10) * 16 + hh) * 1024 + (r0g & 1023)) << 6) + dd;
            ia1 = ((((long)(r1g >> 10) * 16 + hh) * 1024 + (r1g & 1023)) << 6) + dd;
        } else {
            ia0 = (long)(m0 + sr) * lda + kk;
            ia1 = (long)(m0 + sr + 64) * lda + kk;
        }
        long iw0 = w_off + (long)(n0 + sr) * ldw + kk;
        long iw1 = w_off + (long)(n0 + sr + 64) * ldw + kk;
        __syncthreads();
        if (a_f32) {
            *(bf16x8*)&As[sr * LDT + sc]        = load8f((const float*)A + ia0);
            *(bf16x8*)&As[(sr + 64) * LDT + sc] = load8f((const float*)A + ia1);
        } else {
            *(bf16x8*)&As[sr * LDT + sc]        = *(const bf16x8*)((const bf16_t*)A + ia0);
            *(bf16x8*)&As[(sr + 64) * LDT + sc] = *(const bf16x8*)((const bf16_t*)A + ia1);
        }
        *(bf16x8*)&Bs[sr * LDT + sc]        = load8f(W + iw0);
        *(bf16x8*)&Bs[(sr + 64) * LDT + sc] = load8f(W + iw1);
        __syncthreads();
        bf16x8 afr[4], bfr[4];
        for (int i = 0; i < 4; i++)
            afr[i] = *(const bf16x8*)&As[(wr + i * 16 + l15) * LDT + quad * 8];
        for (int j = 0; j < 4; j++)
            bfr[j] = *(const bf16x8*)&Bs[(wc + j * 16 + l15) * LDT + quad * 8];
        for (int i = 0; i < 4; i++)
            for (int j = 0; j < 4; j++)
                acc[i][j] = __builtin_amdgcn_mfma_f32_16x16x32_bf16(
                    afr[i], bfr[j], acc[i][j], 0, 0, 0);
    }

    int rb = quad << 2;
    for (int i = 0; i < 4; i++) {
        for (int j = 0; j < 4; j++) {
            int col = n0 + wc + (j << 4) + l15;
            float bv = bias ? bias[b_off + col] : 0.0f;
            for (int r = 0; r < 4; r++) {
                int row = m0 + wr + (i << 4) + rb + r;
                float v = acc[i][j][r] + bv;
                if (do_relu) v = fmaxf(v, 0.0f);
                long idx = (long)row * N + col;
                if (resid) v += resid[idx];
                if (out_f32) out_f32[idx] = v;
                if (out_b16) out_b16[idx] = (bf16_t)v;
                if (out_hf32 || out_hb16) {
                    int bb = row >> 10, ss = row & 1023, hh = col >> 6, dd = col & 63;
                    long hidx = (((long)bb * 16 + hh) * 1024 + ss) * 64 + dd;
                    if (out_hf32) out_hf32[hidx] = v;
                    if (out_hb16) out_hb16[hidx] = (bf16_t)v;
                }
            }
        }
    }
}

// ---------------------------------------------------------------------------
// FAST MFMA flash attention (fast path only).
// Q bf16 head [BH,S,64]; K bf16 head; V bf16 TRANSPOSED [BH][64][S].
// 4 waves/block, wave w owns Q rows [w*16, w*16+16). Q held in registers
// (A-fragment loaded directly from global: row=wr+l15, k=quad*8+ks*32).
// K/V tile staged to LDS via coalesced b128 (no in-kernel transpose: V is
// pre-transposed by the producing GEMM). Register preload of tile t+1
// hides HBM/L2 latency under compute (T14). 2 barriers/tile: the
// softmax->PV barrier is dropped (each wave reads only its own Ps rows;
// lgkmcnt(0)+sched_barrier guard compiler reordering).
// ---------------------------------------------------------------------------
__global__ __launch_bounds__(256) void attn_fast(
    const bf16_t* __restrict__ Q, const bf16_t* __restrict__ K,
    const bf16_t* __restrict__ V, bf16_t* __restrict__ AO,
    int Sk, int causal)
{
    __shared__ __align__(16) bf16_t Ks[64 * 72];
    __shared__ __align__(16) bf16_t Vt[64 * 72];   // [d][k], pre-transposed
    __shared__ __align__(16) bf16_t Ps[64 * 72];

    int tid = threadIdx.x;
    int qt = blockIdx.x, bh = blockIdx.y;
    int w = tid >> 6, lane = tid & 63;
    int l15 = lane & 15, quad = lane >> 4;
    int wr = w << 4;
    int rowq = wr + (quad << 2);

    // Q fragments in registers
    const bf16_t* Qb = Q + ((long)bh * 1024 + (qt << 6)) * 64;
    bf16x8 aq0 = *(const bf16x8*)&Qb[(wr + l15) * 64 + (quad << 3)];
    bf16x8 aq1 = *(const bf16x8*)&Qb[(wr + l15) * 64 + (quad << 3) + 32];

    float m_i[4] = {-1e30f, -1e30f, -1e30f, -1e30f};
    float l_i[4] = {0.f, 0.f, 0.f, 0.f};
    f32x4 o_acc[4];
    for (int j = 0; j < 4; j++) o_acc[j] = (f32x4){0.f, 0.f, 0.f, 0.f};

    int nt = causal ? (qt + 1) : (Sk >> 6);
    long kb = (long)bh * Sk * 64;   // K head base
    long vb = (long)bh * 64 * Sk;   // V^T base

    int r = tid >> 2, c16 = (tid & 3) << 4;

    // preload tile 0 into registers
    bf16x8 kr0, kr1, vr0, vr1;
    {
        const bf16_t* kp = K + kb + (long)r * 64 + c16;
        const bf16_t* vp = V + vb + (long)r * Sk + c16;
        kr0 = *(const bf16x8*)kp;       kr1 = *(const bf16x8*)(kp + 8);
        vr0 = *(const bf16x8*)vp;       vr1 = *(const bf16x8*)(vp + 8);
    }

    for (int kt = 0; kt < nt; kt++) {
        __syncthreads();   // previous tile's Ks/Vt fully consumed
        *(bf16x8*)&Ks[r * 72 + c16]     = kr0;
        *(bf16x8*)&Ks[r * 72 + c16 + 8] = kr1;
        *(bf16x8*)&Vt[r * 72 + c16]     = vr0;
        *(bf16x8*)&Vt[r * 72 + c16 + 8] = vr1;
        if (kt + 1 < nt) {
            const bf16_t* kp = K + kb + (((long)(kt + 1) << 6) + r) * 64 + c16;
            const bf16_t* vp = V + vb + (long)r * Sk + ((kt + 1) << 6) + c16;
            kr0 = *(const bf16x8*)kp;   kr1 = *(const bf16x8*)(kp + 8);
            vr0 = *(const bf16x8*)vp;   vr1 = *(const bf16x8*)(vp + 8);
        }
        __syncthreads();

        // ---- scores: S = (Q K^T) * 0.125 ----
        f32x4 s[4];
        for (int j = 0; j < 4; j++) s[j] = (f32x4){0.f, 0.f, 0.f, 0.f};
        for (int j = 0; j < 4; j++) {
            bf16x8 bk0 = *(const bf16x8*)&Ks[((j << 4) + l15) * 72 + (quad << 3)];
            bf16x8 bk1 = *(const bf16x8*)&Ks[((j << 4) + l15) * 72 + (quad << 3) + 32];
            s[j] = __builtin_amdgcn_mfma_f32_16x16x32_bf16(aq0, bk0, s[j], 0, 0, 0);
            s[j] = __builtin_amdgcn_mfma_f32_16x16x32_bf16(aq1, bk1, s[j], 0, 0, 0);
        }

        // ---- online softmax (rows rowq..rowq+3, cols j*16+l15) ----
        int diag = causal && (kt == qt);
        for (int rr = 0; rr < 4; rr++) {
            float sv[4];
            for (int j = 0; j < 4; j++) {
                float x = s[j][rr] * 0.125f;
                if (diag && ((j << 4) + l15 > rowq + rr)) x = -1e30f;
                sv[j] = x;
            }
            float mx = fmaxf(fmaxf(sv[0], sv[1]), fmaxf(sv[2], sv[3]));
            for (int off = 1; off < 16; off <<= 1) mx = fmaxf(mx, __shfl_xor(mx, off));
            float mnew = fmaxf(m_i[rr], mx);
            float alpha = __expf(m_i[rr] - mnew);
            float p0 = __expf(sv[0] - mnew), p1 = __expf(sv[1] - mnew);
            float p2 = __expf(sv[2] - mnew), p3 = __expf(sv[3] - mnew);
            float rsum = p0 + p1 + p2 + p3;
            for (int off = 1; off < 16; off <<= 1) rsum += __shfl_xor(rsum, off);
            m_i[rr] = mnew;
            l_i[rr] = l_i[rr] * alpha + rsum;
            for (int j = 0; j < 4; j++) o_acc[j][rr] *= alpha;
            bf16_t* pr = &Ps[(rowq + rr) * 72 + l15];
            pr[0]  = (bf16_t)p0; pr[16] = (bf16_t)p1;
            pr[32] = (bf16_t)p2; pr[48] = (bf16_t)p3;
        }
        // Ps rows are wave-local: no s_barrier needed, but the ds_writes
        // must complete & not be reordered past the ds_reads below.
        asm volatile("s_waitcnt lgkmcnt(0)" ::: "memory");
        __builtin_amdgcn_sched_barrier(0);

        // ---- O += P V ----
        for (int ks = 0; ks < 2; ks++) {
            int sl = (quad + (ks << 2)) << 3;
            bf16x8 ap = *(const bf16x8*)&Ps[(wr + l15) * 72 + sl];
            for (int j = 0; j < 4; j++) {
                bf16x8 bv = *(const bf16x8*)&Vt[((j << 4) + l15) * 72 + sl];
                o_acc[j] = __builtin_amdgcn_mfma_f32_16x16x32_bf16(ap, bv, o_acc[j], 0, 0, 0);
            }
        }
    }

    bf16_t* Ob = AO + ((long)bh * 1024 + (qt << 6)) * 64;
    for (int rr = 0; rr < 4; rr++) {
        float inv = 1.0f / l_i[rr];
        for (int j = 0; j < 4; j++)
            Ob[(rowq + rr) * 64 + (j << 4) + l15] = (bf16_t)(o_acc[j][rr] * inv);
    }
}

// ---------------------------------------------------------------------------
// LEGACY flash attention (fallback path): fp32 or bf16 HEAD-layout K/V,
// in-kernel V transpose. Unchanged from r3 (known passing).
// ---------------------------------------------------------------------------
__global__ __launch_bounds__(256) void attn_kernel(
    const bf16_t* __restrict__ Q, const void* __restrict__ K,
    const void* __restrict__ V, bf16_t* __restrict__ AO,
    int Sk, int causal, int kv_f32)
{
    __shared__ __align__(16) bf16_t Qs[64 * 72];
    __shared__ __align__(16) bf16_t Ks[64 * 72];
    __shared__ __align__(16) bf16_t Vt[64 * 72];
    __shared__ __align__(16) bf16_t Ps[64 * 72];

    int tid = threadIdx.x;
    int qt = blockIdx.x, bh = blockIdx.y;
    int w = tid >> 6, lane = tid & 63;
    int l15 = lane & 15, quad = lane >> 4;
    int wr = w << 4;
    int rowq = wr + (quad << 2);

    {
        int r = tid >> 2, c16 = (tid & 3) << 4;
        const bf16_t* Qb = Q + ((long)bh * 1024 + qt * 64) * 64;
        bf16x8 a = *(const bf16x8*)&Qb[r * 64 + c16];
        bf16x8 b = *(const bf16x8*)&Qb[r * 64 + c16 + 8];
        *(bf16x8*)&Qs[r * 72 + c16] = a;
        *(bf16x8*)&Qs[r * 72 + c16 + 8] = b;
    }

    float m_i[4] = {-1e30f, -1e30f, -1e30f, -1e30f};
    float l_i[4] = {0.f, 0.f, 0.f, 0.f};
    f32x4 o_acc[4];
    for (int j = 0; j < 4; j++) o_acc[j] = (f32x4){0.f, 0.f, 0.f, 0.f};

    int nt = causal ? (qt + 1) : (Sk >> 6);
    long kvbase = (long)bh * Sk * 64;

    for (int kt = 0; kt < nt; kt++) {
        __syncthreads();
        {
            int r = tid >> 2, c16 = (tid & 3) << 4;
            long off = kvbase + (long)((kt << 6) + r) * 64 + c16;
            bf16x8 k0, k1, v0, v1;
            if (kv_f32) {
                const float* kp = (const float*)K + off;
                const float* vp = (const float*)V + off;
                k0 = load8f(kp); k1 = load8f(kp + 8);
                v0 = load8f(vp); v1 = load8f(vp + 8);
            } else {
                k0 = *(const bf16x8*)((const bf16_t*)K + off);
                k1 = *(const bf16x8*)((const bf16_t*)K + off + 8);
                v0 = *(const bf16x8*)((const bf16_t*)V + off);
                v1 = *(const bf16x8*)((const bf16_t*)V + off + 8);
            }
            *(bf16x8*)&Ks[r * 72 + c16] = k0;
            *(bf16x8*)&Ks[r * 72 + c16 + 8] = k1;
            for (int i = 0; i < 8; i++) {
                Vt[(c16 + i) * 72 + r]     = v0[i];
                Vt[(c16 + 8 + i) * 72 + r] = v1[i];
            }
        }
        __syncthreads();

        f32x4 s[4];
        for (int j = 0; j < 4; j++) s[j] = (f32x4){0.f, 0.f, 0.f, 0.f};
        for (int ks = 0; ks < 2; ks++) {
            int sl = (quad + (ks << 2)) << 3;
            bf16x8 aq = *(const bf16x8*)&Qs[(wr + l15) * 72 + sl];
            for (int j = 0; j < 4; j++) {
                bf16x8 bk = *(const bf16x8*)&Ks[((j << 4) + l15) * 72 + sl];
                s[j] = __builtin_amdgcn_mfma_f32_16x16x32_bf16(aq, bk, s[j], 0, 0, 0);
            }
        }

        int diag = causal && (kt == qt);
        for (int rr = 0; rr < 4; rr++) {
            float sv[4];
            for (int j = 0; j < 4; j++) {
                float x = s[j][rr] * 0.125f;
                if (diag && ((j << 4) + l15 > rowq + rr)) x = -1e30f;
                sv[j] = x;
            }
            float mx = fmaxf(fmaxf(sv[0], sv[1]), fmaxf(sv[2], sv[3]));
            for (int off = 1; off < 16; off <<= 1) mx = fmaxf(mx, __shfl_xor(mx, off));
            float mnew = fmaxf(m_i[rr], mx);
            float alpha = __expf(m_i[rr] - mnew);
            float p0 = __expf(sv[0] - mnew), p1 = __expf(sv[1] - mnew);
            float p2 = __expf(sv[2] - mnew), p3 = __expf(sv[3] - mnew);
            float rsum = p0 + p1 + p2 + p3;
            for (int off = 1; off < 16; off <<= 1) rsum += __shfl_xor(rsum, off);
            m_i[rr] = mnew;
            l_i[rr] = l_i[rr] * alpha + rsum;
            for (int j = 0; j < 4; j++) o_acc[j][rr] *= alpha;
            bf16_t* pr = &Ps[(rowq + rr) * 72 + l15];
            pr[0]  = (bf16_t)p0; pr[16] = (bf16_t)p1;
            pr[32] = (bf16_t)p2; pr[48] = (bf16_t)p3;
        }
        __syncthreads();

        for (int ks = 0; ks < 2; ks++) {
            int sl = (quad + (ks << 2)) << 3;
            bf16x8 ap = *(const bf16x8*)&Ps[(wr + l15) * 72 + sl];
            for (int j = 0; j < 4; j++) {
                bf16x8 bv = *(const bf16x8*)&Vt[((j << 4) + l15) * 72 + sl];
                o_acc[j] = __builtin_amdgcn_mfma_f32_16x16x32_bf16(ap, bv, o_acc[j], 0, 0, 0);
            }
        }
    }

    bf16_t* Ob = AO + ((long)bh * 1024 + qt * 64) * 64;
    for (int rr = 0; rr < 4; rr++) {
        float inv = 1.0f / l_i[rr];
        for (int j = 0; j < 4; j++)
            Ob[(rowq + rr) * 64 + (j << 4) + l15] = (bf16_t)(o_acc[j][rr] * inv);
    }
}

// ---------------------------------------------------------------------------
extern "C" void kernel_launch(void* const* d_in, const int* in_sizes, int n_in,
                              void* d_out, int out_size, void* d_ws, size_t ws_size,
                              hipStream_t stream)
{
    (void)in_sizes; (void)n_in; (void)out_size;
    const float* tgt       = (const float*)d_in[0];
    const float* mem       = (const float*)d_in[1];
    const float* Wq        = (const float*)d_in[2];
    const float* Wk        = (const float*)d_in[3];
    const float* Wv        = (const float*)d_in[4];
    const float* Wo        = (const float*)d_in[5];
    const float* mha_in_w  = (const float*)d_in[6];
    const float* mha_in_b  = (const float*)d_in[7];
    const float* mha_out_w = (const float*)d_in[8];
    const float* mha_out_b = (const float*)d_in[9];
    const float* W1        = (const float*)d_in[10];
    const float* b1        = (const float*)d_in[11];
    const float* W2        = (const float*)d_in[12];
    const float* b2        = (const float*)d_in[13];
    const float* g1        = (const float*)d_in[14];
    const float* be1       = (const float*)d_in[15];
    const float* g2        = (const float*)d_in[16];
    const float* be2       = (const float*)d_in[17];
    const float* g3        = (const float*)d_in[18];
    const float* be3       = (const float*)d_in[19];

    float* out_x = (float*)d_out;
    float* out_k = out_x + (1 << 22);
    float* out_v = out_k + (1 << 22);

    bf16_t* R0 = (bf16_t*)d_ws;
    bf16_t* R1 = R0 + (1 << 22);
    bf16_t* R2 = R1 + (1 << 22);

    dim3 blk(256);
    dim3 blk5(512);
    dim3 gA(16, 64);

    if (ws_size >= ((size_t)96 << 20)) {
        // ---------------- FAST PATH ----------------
        bf16_t* Hff  = R2 + (1 << 22);                              // [24,56) MB
        bf16_t* Wb   = (bf16_t*)((char*)d_ws + ((size_t)56 << 20)); // [56,88)
        bf16_t* memb = Wb + 16777216;                               // [88,96)
        bf16_t* saKb = Hff;                 // [24,32) MB — bf16 K head
        bf16_t* saVb = Hff + (1 << 22);     // [32,40) MB — bf16 V TRANSPOSED
        const long WO_OFF  = 3145728;
        const long CQ_OFF  = 4194304;
        const long CKV_OFF = 5242880;
        const long CO_OFF  = 7340032;
        const long W1_OFF  = 8388608;
        const long W2_OFF  = 12582912;

        conv_kernel<<<10240, blk, 0, stream>>>(Wq, Wk, Wv, Wo, mha_in_w,
                                               mha_out_w, W1, W2, mem, Wb);

        // ---- self-attention ----
        ln_kernel<<<4096, blk, 0, stream>>>(tgt, g1, be1, R0);
        gemm_big<8><<<dim3(12, 16), blk5, 0, stream>>>(R0, 1024, Wb, 0, 1024, 1024,
                                                       nullptr, 0, nullptr,
                                                       R1, out_k, out_v, 1, 3072, 0,
                                                       saKb, saVb);
        attn_fast<<<gA, blk, 0, stream>>>(R1, saKb, saVb, R1, 1024, 1);
        gemm_fast<2><<<dim3(16, 32), blk, 0, stream>>>(R1, 0, 1, Wb, WO_OFF, 1024, 1024,
                                                       nullptr, 0, tgt,
                                                       out_x, nullptr, nullptr, 0, 1024, 0,
                                                       nullptr, nullptr);

        // ---- cross-attention ----
        ln_kernel<<<4096, blk, 0, stream>>>(out_x, g2, be2, R0);
        gemm_fast<2><<<dim3(16, 32), blk, 0, stream>>>(R0, 1024, 0, Wb, CQ_OFF, 1024, 1024,
                                                       mha_in_b, 0, nullptr,
                                                       nullptr, nullptr, R1, 0, 1024, 0,
                                                       nullptr, nullptr);
        gemm_big<4><<<dim3(8, 32), blk5, 0, stream>>>(memb, 1024, Wb, CKV_OFF, 1024, 1024,
                                                      mha_in_b, 1024, nullptr,
                                                      R2, R0, nullptr, 2, 2048, 0,
                                                      nullptr, nullptr);
        attn_fast<<<gA, blk, 0, stream>>>(R1, R2, R0, R1, 1024, 0);
        gemm_fast<2><<<dim3(16, 32), blk, 0, stream>>>(R1, 0, 1, Wb, CO_OFF, 1024, 1024,
                                                       mha_out_b, 0, out_x,
                                                       out_x, nullptr, nullptr, 0, 1024, 0,
                                                       nullptr, nullptr);

        // ---- FFN ----
        ln_kernel<<<4096, blk, 0, stream>>>(out_x, g3, be3, R0);
        gemm_big<8><<<dim3(16, 16), blk5, 0, stream>>>(R0, 1024, Wb, W1_OFF, 1024, 1024,
                                                       b1, 0, nullptr,
                                                       nullptr, Hff, nullptr, 0, 4096, 1,
                                                       nullptr, nullptr);
        gemm_fast<2><<<dim3(16, 32), blk, 0, stream>>>(Hff, 4096, 0, Wb, W2_OFF, 4096, 4096,
                                                       b2, 0, out_x,
                                                       out_x, nullptr, nullptr, 0, 1024, 0,
                                                       nullptr, nullptr);
        return;
    }

    // ---------------- FALLBACK (round-5, known passing) ----------------
    dim3 gD(8, 32);
    dim3 gF1(32, 16);
    dim3 gF2(8, 16);

    ln_kernel<<<4096, blk, 0, stream>>>(tgt, g1, be1, R0);
    gemm_nt<<<gD, blk, 0, stream>>>(R0, 1024, 0, 0, Wq, 0, 1024, 1024,
                                    nullptr, 0, nullptr, nullptr, nullptr,
                                    nullptr, R1, 1024, 0);
    gemm_nt<<<gD, blk, 0, stream>>>(R0, 1024, 0, 0, Wk, 0, 1024, 1024,
                                    nullptr, 0, nullptr, nullptr, nullptr,
                                    out_k, nullptr, 1024, 0);
    gemm_nt<<<gD, blk, 0, stream>>>(R0, 1024, 0, 0, Wv, 0, 1024, 1024,
                                    nullptr, 0, nullptr, nullptr, nullptr,
                                    out_v, nullptr, 1024, 0);
    attn_kernel<<<gA, blk, 0, stream>>>(R1, out_k, out_v, R1, 1024, 1, 1);
    gemm_nt<<<gD, blk, 0, stream>>>(R1, 0, 1, 0, Wo, 0, 1024, 1024,
                                    nullptr, 0, tgt, out_x, nullptr,
                                    nullptr, nullptr, 1024, 0);

    ln_kernel<<<4096, blk, 0, stream>>>(out_x, g2, be2, R0);
    gemm_nt<<<gD, blk, 0, stream>>>(R0, 1024, 0, 0, mha_in_w, 0, 1024, 1024,
                                    mha_in_b, 0, nullptr, nullptr, nullptr,
                                    nullptr, R1, 1024, 0);
    gemm_nt<<<gD, blk, 0, stream>>>(mem, 1024, 0, 1, mha_in_w, (long)1 << 20, 1024, 1024,
                                    mha_in_b, 1024, nullptr, nullptr, nullptr,
                                    nullptr, R2, 1024, 0);
    gemm_nt<<<gD, blk, 0, stream>>>(mem, 1024, 0, 1, mha_in_w, (long)2 << 20, 1024, 1024,
                                    mha_in_b, 2048, nullptr, nullptr, nullptr,
                                    nullptr, R0, 1024, 0);
    attn_kernel<<<gA, blk, 0, stream>>>(R1, R2, R0, R1, 1024, 0, 0);
    gemm_nt<<<gD, blk, 0, stream>>>(R1, 0, 1, 0, mha_out_w, 0, 1024, 1024,
                                    mha_out_b, 0, out_x, out_x, nullptr,
                                    nullptr, nullptr, 1024, 0);

    ln_kernel<<<4096, blk, 0, stream>>>(out_x, g3, be3, R0);
    for (int c = 0; c < 2; c++) {
        const bf16_t* Ac = R0 + (long)c * 2048 * 1024;
        bf16_t*       Hc = R1;
        float*        Xc = out_x + (long)c * 2048 * 1024;
        gemm_nt<<<gF1, blk, 0, stream>>>(Ac, 1024, 0, 0, W1, 0, 1024, 1024,
                                         b1, 0, nullptr, nullptr, Hc,
                                         nullptr, nullptr, 4096, 1);
        gemm_nt<<<gF2, blk, 0, stream>>>(Hc, 4096, 0, 0, W2, 0, 4096, 4096,
                                         b2, 0, Xc, Xc, nullptr,
                                         nullptr, nullptr, 1024, 0);
    }
}

// Round 6
// 600.940 us; speedup vs baseline: 2.0265x; 1.0374x over previous
//
#include <hip/hip_runtime.h>

typedef __bf16 bf16_t;
typedef unsigned int u32;
typedef __attribute__((ext_vector_type(8))) __bf16 bf16x8;
typedef __attribute__((ext_vector_type(4))) __bf16 bf16x4;
typedef __attribute__((ext_vector_type(4))) float f32x4;

// B=4, S=SM=1024, D=1024, H=16, HD=64, DFF=4096; M = B*S = 4096 rows.
// Inputs fp32; d_out fp32 (x, sa_k, sa_v). Internals bf16 (MFMA).
// FAST PATH (ws >= 96MB): bf16 weights cached in ws.

__device__ __forceinline__ bf16x8 load8f(const float* f) {
    float4 a = *(const float4*)f;
    float4 b = *(const float4*)(f + 4);
    bf16x8 r;
    r[0] = (bf16_t)a.x; r[1] = (bf16_t)a.y; r[2] = (bf16_t)a.z; r[3] = (bf16_t)a.w;
    r[4] = (bf16_t)b.x; r[5] = (bf16_t)b.y; r[6] = (bf16_t)b.z; r[7] = (bf16_t)b.w;
    return r;
}

// async 16B/lane global->LDS; LDS dest = wave-uniform base + lane*16
__device__ __forceinline__ void gll16(const void* g, const void* l) {
    __builtin_amdgcn_global_load_lds(
        (const __attribute__((address_space(1))) u32*)(unsigned long long)g,
        (__attribute__((address_space(3))) u32*)(unsigned int)(unsigned long long)l,
        16, 0, 0);
}

// ---------------------------------------------------------------------------
// fp32 -> bf16 weight/mem conversion (one contiguous buffer).
// ---------------------------------------------------------------------------
__global__ __launch_bounds__(256) void conv_kernel(
    const float* __restrict__ Wq, const float* __restrict__ Wk,
    const float* __restrict__ Wv, const float* __restrict__ Wo,
    const float* __restrict__ Wio, const float* __restrict__ Woo,
    const float* __restrict__ W1, const float* __restrict__ W2,
    const float* __restrict__ mem, bf16_t* __restrict__ dst)
{
    long e = ((long)blockIdx.x * 256 + threadIdx.x) * 8;
    const float* s; long o;
    if      (e <  1048576) { s = Wq;  o = e; }
    else if (e <  2097152) { s = Wk;  o = e -  1048576; }
    else if (e <  3145728) { s = Wv;  o = e -  2097152; }
    else if (e <  4194304) { s = Wo;  o = e -  3145728; }
    else if (e <  7340032) { s = Wio; o = e -  4194304; }
    else if (e <  8388608) { s = Woo; o = e -  7340032; }
    else if (e < 12582912) { s = W1;  o = e -  8388608; }
    else if (e < 16777216) { s = W2;  o = e - 12582912; }
    else                   { s = mem; o = e - 16777216; }
    *(bf16x8*)&dst[e] = load8f(s + o);
}

// ---------------------------------------------------------------------------
// LayerNorm: one block per fp32 row of 1024 -> bf16 out (fp32 math).
// ---------------------------------------------------------------------------
__global__ __launch_bounds__(256) void ln_kernel(
    const float* __restrict__ x,
    const float* __restrict__ g, const float* __restrict__ be,
    bf16_t* __restrict__ out)
{
    int row = blockIdx.x, t = threadIdx.x;
    float4 q = *(const float4*)(x + (long)row * 1024 + t * 4);
    float v[4] = {q.x, q.y, q.z, q.w};
    float s = v[0] + v[1] + v[2] + v[3];
    float s2 = v[0]*v[0] + v[1]*v[1] + v[2]*v[2] + v[3]*v[3];
    for (int off = 32; off > 0; off >>= 1) {
        s  += __shfl_down(s, off);
        s2 += __shfl_down(s2, off);
    }
    __shared__ float rs[4], rq[4];
    int w = t >> 6;
    if ((t & 63) == 0) { rs[w] = s; rq[w] = s2; }
    __syncthreads();
    s  = rs[0] + rs[1] + rs[2] + rs[3];
    s2 = rq[0] + rq[1] + rq[2] + rq[3];
    float mean = s * (1.0f / 1024.0f);
    float var  = s2 * (1.0f / 1024.0f) - mean * mean;
    float rstd = rsqrtf(var + 1e-5f);
    int c = t * 4;
    for (int i = 0; i < 4; i++)
        out[(long)row * 1024 + c + i] =
            (bf16_t)((v[i] - mean) * rstd * g[c + i] + be[c + i]);
}

// ---------------------------------------------------------------------------
// BIG NT GEMM v2: 128x256 tile, 8 waves (512 thr), BK=64, THREE LDS buffers
// (147KB), counted-vmcnt pipeline (T3/T4): tile t+2's staging issued during
// tile t; boundary = s_waitcnt vmcnt(6) (drains t+1's group, leaves t+2 in
// flight) + ONE raw s_barrier. Never vmcnt(0) in the main loop (r5
// post-mortem: the per-step drain was the latency bottleneck; m218 measured
// counted-vs-drain0 = +38..73%). Buffer (t+2)%3 == (t-1)%3: its readers all
// passed the t-1/t barrier before staging issues — safe with one barrier.
// Wave w: wm=w>>2 (2 M-halves of 64), wn=w&3 (4 N-quarters of 64).
// mode 0: o0=f32 rm | o1=b16 rm | o2=b16 head
// mode 1 (QKV): seg0->o0 b16 head; seg1->o1 f32 head (+o3 b16 head);
//               seg2->o2 f32 head (+o4 b16 V-TRANSPOSED [BH][64][S])
// mode 2 (crossKV): seg0->o0 b16 head, seg1->o1 b16 V-TRANSPOSED
// ---------------------------------------------------------------------------
__global__ __launch_bounds__(512, 2) void gemm_big128(
    const bf16_t* __restrict__ A, int lda,
    const bf16_t* __restrict__ Wb, long w_off, int ldw, int K,
    const float* __restrict__ bias, long b_off,
    const float* resid,
    void* o0, void* o1, void* o2, int mode, int N, int do_relu,
    void* o3, void* o4)
{
    __shared__ __align__(16) bf16_t As[3][128 * 64];
    __shared__ __align__(16) bf16_t Bs[3][256 * 64];
    int tid = threadIdx.x;
    int lin = blockIdx.y * gridDim.x + blockIdx.x;
    int mb = lin % gridDim.y, nb = lin / gridDim.y;  // m fastest -> XCD-local
    int m0 = mb << 7, n0 = nb << 8;
    int w = tid >> 6, lane = tid & 63;
    int l15 = lane & 15, quad = lane >> 4;
    int wm = w >> 2, wn = w & 3;
    int srow = lane >> 3;                 // row within 8-row staging group
    int cgo  = ((lane & 7) ^ srow) << 3;  // swizzled source chunk (elems)

    const bf16_t* Wg = Wb + w_off;
    int nk = K >> 6;

    f32x4 acc[4][4];
    #pragma unroll
    for (int i = 0; i < 4; i++)
        #pragma unroll
        for (int j = 0; j < 4; j++)
            acc[i][j] = (f32x4){0.f, 0.f, 0.f, 0.f};

    // per wave per tile: 2 A-gll16 + 4 B-gll16 = 6 loads (vmcnt unit)
#define STAGEB(P, KK)                                                         \
    _Pragma("unroll")                                                         \
    for (int g = 0; g < 2; g++) {                                             \
        int rg = ((g << 3) + w) << 3;                                         \
        gll16(A  + (long)(m0 + rg + srow) * lda + (KK) + cgo, &As[P][rg << 6]); \
    }                                                                         \
    _Pragma("unroll")                                                         \
    for (int g = 0; g < 4; g++) {                                             \
        int rg = ((g << 3) + w) << 3;                                         \
        gll16(Wg + (long)(n0 + rg + srow) * ldw + (KK) + cgo, &Bs[P][rg << 6]); \
    }

    STAGEB(0, 0)
    if (nk > 1) STAGEB(1, 64)
    if (nk > 1) { asm volatile("s_waitcnt vmcnt(6)"); }
    else        { asm volatile("s_waitcnt vmcnt(0)"); }
    __builtin_amdgcn_sched_barrier(0);
    __builtin_amdgcn_s_barrier();
    __builtin_amdgcn_sched_barrier(0);

    int p = 0;
    for (int t = 0; t < nk; t++) {
        bf16x8 bfr[4][2];
        #pragma unroll
        for (int q = 0; q < 2; q++) {
            bf16x8 af[2][2];
            #pragma unroll
            for (int i2 = 0; i2 < 2; i2++)
                #pragma unroll
                for (int ks = 0; ks < 2; ks++) {
                    int row = (wm << 6) + (((q << 1) + i2) << 4) + l15;
                    int sl = ((quad + (ks << 2)) ^ (l15 & 7)) << 3;
                    af[i2][ks] = *(const bf16x8*)&As[p][(row << 6) + sl];
                }
            if (q == 0) {
                #pragma unroll
                for (int j = 0; j < 4; j++)
                    #pragma unroll
                    for (int ks = 0; ks < 2; ks++) {
                        int row = (wn << 6) + (j << 4) + l15;
                        int sl = ((quad + (ks << 2)) ^ (l15 & 7)) << 3;
                        bfr[j][ks] = *(const bf16x8*)&Bs[p][(row << 6) + sl];
                    }
                if (t + 2 < nk) {
                    int s2 = (p + 2 >= 3) ? p - 1 : p + 2;
                    STAGEB(s2, (t + 2) << 6)
                }
            }
            asm volatile("s_waitcnt lgkmcnt(0)");
            __builtin_amdgcn_sched_barrier(0);
            __builtin_amdgcn_s_setprio(1);
            #pragma unroll
            for (int i2 = 0; i2 < 2; i2++)
                #pragma unroll
                for (int j = 0; j < 4; j++)
                    #pragma unroll
                    for (int ks = 0; ks < 2; ks++)
                        acc[(q << 1) + i2][j] = __builtin_amdgcn_mfma_f32_16x16x32_bf16(
                            af[i2][ks], bfr[j][ks], acc[(q << 1) + i2][j], 0, 0, 0);
            __builtin_amdgcn_s_setprio(0);
            __builtin_amdgcn_sched_barrier(0);
        }
        // boundary: drain tile t+1's loads only (t+2 stays in flight)
        if (t + 2 < nk)      { asm volatile("s_waitcnt vmcnt(6)"); }
        else if (t + 1 < nk) { asm volatile("s_waitcnt vmcnt(0)"); }
        __builtin_amdgcn_sched_barrier(0);
        __builtin_amdgcn_s_barrier();
        __builtin_amdgcn_sched_barrier(0);
        p = (p == 2) ? 0 : p + 1;
    }
#undef STAGEB

    int rb = quad << 2;  // C/D: col = lane&15, row = quad*4 + reg
    for (int i = 0; i < 4; i++) {
        for (int j = 0; j < 4; j++) {
            int col = n0 + (wn << 6) + (j << 4) + l15;
            float bv = bias ? bias[b_off + col] : 0.0f;
            int row0 = m0 + (wm << 6) + (i << 4) + rb;
            float vv[4];
            for (int r = 0; r < 4; r++) {
                float v = acc[i][j][r] + bv;
                if (do_relu) v = fmaxf(v, 0.0f);
                vv[r] = v;
            }
            if (mode == 0) {
                for (int r = 0; r < 4; r++) {
                    int row = row0 + r;
                    long idx = (long)row * N + col;
                    float v = vv[r];
                    if (resid) v += resid[idx];
                    if (o0) ((float*)o0)[idx] = v;
                    if (o1) ((bf16_t*)o1)[idx] = (bf16_t)v;
                    if (o2) {
                        long hidx = (((long)(row >> 10) * 16 + (col >> 6)) * 1024
                                     + (row & 1023)) * 64 + (col & 63);
                        ((bf16_t*)o2)[hidx] = (bf16_t)v;
                    }
                }
            } else {
                int seg = col >> 10, c = col & 1023;
                long hb = (long)(row0 >> 10) * 16 + (c >> 6);
                long hidx0 = (hb * 1024 + (row0 & 1023)) * 64 + (c & 63);
                if (mode == 1) {
                    if (seg == 0) {
                        for (int r = 0; r < 4; r++)
                            ((bf16_t*)o0)[hidx0 + r * 64] = (bf16_t)vv[r];
                    } else if (seg == 1) {
                        for (int r = 0; r < 4; r++) {
                            ((float*)o1)[hidx0 + r * 64] = vv[r];
                            if (o3) ((bf16_t*)o3)[hidx0 + r * 64] = (bf16_t)vv[r];
                        }
                    } else {
                        for (int r = 0; r < 4; r++)
                            ((float*)o2)[hidx0 + r * 64] = vv[r];
                        if (o4) {
                            long vt0 = (hb * 64 + (c & 63)) * 1024 + (row0 & 1023);
                            bf16x4 pk;
                            for (int r = 0; r < 4; r++) pk[r] = (bf16_t)vv[r];
                            *(bf16x4*)&((bf16_t*)o4)[vt0] = pk;
                        }
                    }
                } else {
                    if (seg == 0) {
                        for (int r = 0; r < 4; r++)
                            ((bf16_t*)o0)[hidx0 + r * 64] = (bf16_t)vv[r];
                    } else {
                        long vt0 = (hb * 64 + (c & 63)) * 1024 + (row0 & 1023);
                        bf16x4 pk;
                        for (int r = 0; r < 4; r++) pk[r] = (bf16_t)vv[r];
                        *(bf16x4*)&((bf16_t*)o1)[vt0] = pk;
                    }
                }
            }
        }
    }
}

// ---------------------------------------------------------------------------
// FAST NT GEMM v5: 128 x (NJ*32) tile, BK=64, THREE LDS buffers + counted
// vmcnt (same pipeline as gemm_big128; 6 gll16/wave/tile for NJ=2 -> 72KB
// LDS, 2 blocks/CU). One raw s_barrier per K-step, no vmcnt(0) in loop.
// Used for the N=1024 GEMMs (WO, CQ, CO, W2).
// ---------------------------------------------------------------------------
template<int NJ>
__global__ __launch_bounds__(256) void gemm_fast(
    const bf16_t* __restrict__ A, int lda, int a_head,
    const bf16_t* __restrict__ Wb, long w_off, int ldw, int K,
    const float* __restrict__ bias, long b_off,
    const float* resid,
    void* o0, void* o1, void* o2, int mode, int N, int do_relu,
    void* o3, void* o4)
{
    constexpr int BN = NJ << 5;           // 64
    __shared__ __align__(16) bf16_t As[3][128 * 64];
    __shared__ __align__(16) bf16_t Bs[3][BN * 64];
    int tid = threadIdx.x;
    int lin = blockIdx.y * gridDim.x + blockIdx.x;   // HW dispatch order
    int mb = lin % gridDim.y, nb = lin / gridDim.y;  // m fastest -> A strip XCD-local
    int m0 = mb << 7, n0 = nb * BN;
    int w = tid >> 6, lane = tid & 63;
    int l15 = lane & 15, quad = lane >> 4;
    int wr = (w >> 1) << 6, wc = (w & 1) * (BN >> 1);

    int srow = lane >> 3;                 // row within 8-row staging group
    int cgo  = ((lane & 7) ^ srow) << 3;  // swizzled source chunk offset (elems)

    f32x4 acc[4][NJ];
    for (int i = 0; i < 4; i++)
        for (int j = 0; j < NJ; j++)
            acc[i][j] = (f32x4){0.f, 0.f, 0.f, 0.f};

    const bf16_t* Wg = Wb + w_off;
    int nk = K >> 6;

    // per wave per tile: 4 A-gll16 + NJ B-gll16 = 6 loads for NJ=2
#define STAGE(P, KK)                                                          \
    {                                                                         \
        const bf16_t* Ab; long astr;                                          \
        if (a_head) {                                                         \
            int hh = (KK) >> 6;                                               \
            Ab = A + ((((long)(m0 >> 10)) * 16 + hh) * 1024 + (m0 & 1023)) * 64; \
            astr = 64;                                                        \
        } else {                                                              \
            Ab = A + (long)m0 * lda + (KK);                                   \
            astr = lda;                                                       \
        }                                                                     \
        const bf16_t* Bb = Wg + (long)n0 * ldw + (KK);                        \
        for (int t = 0; t < 4; t++) {                                         \
            int rb2 = (w << 5) + (t << 3);                                    \
            gll16(Ab + (long)(rb2 + srow) * astr + cgo, &As[P][rb2 << 6]);    \
        }                                                                     \
        for (int t = 0; t < NJ; t++) {                                        \
            int rb2 = w * (BN >> 2) + (t << 3);                               \
            gll16(Bb + (long)(rb2 + srow) * ldw + cgo, &Bs[P][rb2 << 6]);     \
        }                                                                     \
    }

#define COMPUTE(P)                                                            \
    for (int ks = 0; ks < 2; ks++) {                                          \
        bf16x8 af[4], bf_[NJ];                                                \
        int gA = quad + (ks << 2);                                            \
        int sl = (gA ^ (l15 & 7)) << 3;                                       \
        for (int i = 0; i < 4; i++)                                           \
            af[i]  = *(const bf16x8*)&As[P][((wr + (i << 4) + l15) << 6) + sl]; \
        for (int j = 0; j < NJ; j++)                                          \
            bf_[j] = *(const bf16x8*)&Bs[P][((wc + (j << 4) + l15) << 6) + sl]; \
        asm volatile("s_waitcnt lgkmcnt(0)");                                 \
        __builtin_amdgcn_sched_barrier(0);                                    \
        __builtin_amdgcn_s_setprio(1);                                        \
        for (int i = 0; i < 4; i++)                                           \
            for (int j = 0; j < NJ; j++)                                      \
                acc[i][j] = __builtin_amdgcn_mfma_f32_16x16x32_bf16(          \
                    af[i], bf_[j], acc[i][j], 0, 0, 0);                       \
        __builtin_amdgcn_s_setprio(0);                                        \
        __builtin_amdgcn_sched_barrier(0);                                    \
    }

    STAGE(0, 0)
    if (nk > 1) STAGE(1, 64)
    if (nk > 1) { asm volatile("s_waitcnt vmcnt(6)"); }
    else        { asm volatile("s_waitcnt vmcnt(0)"); }
    __builtin_amdgcn_sched_barrier(0);
    __builtin_amdgcn_s_barrier();
    __builtin_amdgcn_sched_barrier(0);

    int p = 0;
    for (int kt = 0; kt < nk; kt++) {
        if (kt + 2 < nk) {
            int s2 = (p + 2 >= 3) ? p - 1 : p + 2;
            STAGE(s2, (kt + 2) << 6)
        }
        COMPUTE(p)
        if (kt + 2 < nk)      { asm volatile("s_waitcnt vmcnt(6)"); }
        else if (kt + 1 < nk) { asm volatile("s_waitcnt vmcnt(0)"); }
        __builtin_amdgcn_sched_barrier(0);
        __builtin_amdgcn_s_barrier();
        __builtin_amdgcn_sched_barrier(0);
        p = (p == 2) ? 0 : p + 1;
    }
#undef STAGE
#undef COMPUTE

    int rb = quad << 2;  // C/D: col = lane&15, row = quad*4 + reg
    for (int i = 0; i < 4; i++) {
        for (int j = 0; j < NJ; j++) {
            int col = n0 + wc + (j << 4) + l15;
            float bv = bias ? bias[b_off + col] : 0.0f;
            for (int r = 0; r < 4; r++) {
                int row = m0 + wr + (i << 4) + rb + r;
                float v = acc[i][j][r] + bv;
                if (do_relu) v = fmaxf(v, 0.0f);
                if (mode == 0) {
                    long idx = (long)row * N + col;
                    if (resid) v += resid[idx];
                    if (o0) ((float*)o0)[idx] = v;
                    if (o1) ((bf16_t*)o1)[idx] = (bf16_t)v;
                    if (o2) {
                        long hidx = (((long)(row >> 10) * 16 + (col >> 6)) * 1024
                                     + (row & 1023)) * 64 + (col & 63);
                        ((bf16_t*)o2)[hidx] = (bf16_t)v;
                    }
                } else {
                    int seg = col >> 10, c = col & 1023;
                    long hidx = (((long)(row >> 10) * 16 + (c >> 6)) * 1024
                                 + (row & 1023)) * 64 + (c & 63);
                    if (mode == 1) {
                        if (seg == 0)      ((bf16_t*)o0)[hidx] = (bf16_t)v;
                        else if (seg == 1) {
                            ((float*)o1)[hidx] = v;
                            if (o3) ((bf16_t*)o3)[hidx] = (bf16_t)v;
                        } else {
                            ((float*)o2)[hidx] = v;
                            if (o4) ((bf16_t*)o4)[hidx] = (bf16_t)v;
                        }
                    } else {
                        if (seg == 0)      ((bf16_t*)o0)[hidx] = (bf16_t)v;
                        else               ((bf16_t*)o1)[hidx] = (bf16_t)v;
                    }
                }
            }
        }
    }
}

// ---------------------------------------------------------------------------
// FALLBACK NT GEMM (round-5, fp32 weights) — only if ws < 96MB.
// ---------------------------------------------------------------------------
#define LDT 40

__global__ __launch_bounds__(256) void gemm_nt(
    const void* __restrict__ A, int lda, int a_head, int a_f32,
    const float* __restrict__ W, long w_off, int ldw,
    int K,
    const float* __restrict__ bias, long b_off,
    const float* __restrict__ resid,
    float*  out_f32, bf16_t* __restrict__ out_b16,
    float*  __restrict__ out_hf32, bf16_t* __restrict__ out_hb16,
    int N, int do_relu)
{
    __shared__ bf16_t As[128 * LDT];
    __shared__ bf16_t Bs[128 * LDT];
    int tid = threadIdx.x;
    int m0 = blockIdx.y << 7, n0 = blockIdx.x << 7;
    int wave = tid >> 6, lane = tid & 63;
    int wr = (wave >> 1) << 6;
    int wc = (wave & 1) << 6;
    int l15 = lane & 15, quad = lane >> 4;

    f32x4 acc[4][4];
    for (int i = 0; i < 4; i++)
        for (int j = 0; j < 4; j++)
            acc[i][j] = (f32x4){0.f, 0.f, 0.f, 0.f};

    int sr = tid >> 2;
    int sc = (tid & 3) << 3;

    for (int k0 = 0; k0 < K; k0 += 32) {
        int kk = k0 + sc;
        long ia0, ia1;
        if (a_head) {
            int hh = kk >> 6, dd = kk & 63;
            int r0g = m0 + sr, r1g = r0g + 64;
            ia0 = ((((long)(r0g >> 10) * 16 + hh) * 1024 + (r0g & 1023)) << 6) + dd;
            ia1 = ((((long)(r1g >> 10) * 16 + hh) * 1024 + (r1g & 1023)) << 6) + dd;
        } else {
            ia0 = (long)(m0 + sr) * lda + kk;
            ia1 = (long)(m0 + sr + 64) * lda + kk;
        }
        long iw0 = w_off + (long)(n0 + sr) * ldw + kk;
        long iw1 = w_off + (long)(n0 + sr + 64) * ldw + kk;
        __syncthreads();
        if (a_f32) {
            *(bf16x8*)&As[sr * LDT + sc]        = load8f((const float*)A + ia0);
            *(bf16x8*)&As[(sr + 64) * LDT + sc] = load8f((const float*)A + ia1);
        } else {
            *(bf16x8*)&As[sr * LDT + sc]        = *(const bf16x8*)((const bf16_t*)A + ia0);
            *(bf16x8*)&As[(sr + 64) * LDT + sc] = *(const bf16x8*)((const bf16_t*)A + ia1);
        }
        *(bf16x8*)&Bs[sr * LDT + sc]        = load8f(W + iw0);
        *(bf16x8*)&Bs[(sr + 64) * LDT + sc] = load8f(W + iw1);
        __syncthreads();
        bf16x8 afr[4], bfr[4];
        for (int i = 0; i < 4; i++)
            afr[i] = *(const bf16x8*)&As[(wr + i * 16 + l15) * LDT + quad * 8];
        for (int j = 0; j < 4; j++)
            bfr[j] = *(const bf16x8*)&Bs[(wc + j * 16 + l15) * LDT + quad * 8];
        for (int i = 0; i < 4; i++)
            for (int j = 0; j < 4; j++)
                acc[i][j] = __builtin_amdgcn_mfma_f32_16x16x32_bf16(
                    afr[i], bfr[j], acc[i][j], 0, 0, 0);
    }

    int rb = quad << 2;
    for (int i = 0; i < 4; i++) {
        for (int j = 0; j < 4; j++) {
            int col = n0 + wc + (j << 4) + l15;
            float bv = bias ? bias[b_off + col] : 0.0f;
            for (int r = 0; r < 4; r++) {
                int row = m0 + wr + (i << 4) + rb + r;
                float v = acc[i][j][r] + bv;
                if (do_relu) v = fmaxf(v, 0.0f);
                long idx = (long)row * N + col;
                if (resid) v += resid[idx];
                if (out_f32) out_f32[idx] = v;
                if (out_b16) out_b16[idx] = (bf16_t)v;
                if (out_hf32 || out_hb16) {
                    int bb = row >> 10, ss = row & 1023, hh = col >> 6, dd = col & 63;
                    long hidx = (((long)bb * 16 + hh) * 1024 + ss) * 64 + dd;
                    if (out_hf32) out_hf32[hidx] = v;
                    if (out_hb16) out_hb16[hidx] = (bf16_t)v;
                }
            }
        }
    }
}

// ---------------------------------------------------------------------------
// FAST MFMA flash attention (fast path only). Unchanged from r5.
// Q bf16 head [BH,S,64]; K bf16 head; V bf16 TRANSPOSED [BH][64][S].
// ---------------------------------------------------------------------------
__global__ __launch_bounds__(256) void attn_fast(
    const bf16_t* __restrict__ Q, const bf16_t* __restrict__ K,
    const bf16_t* __restrict__ V, bf16_t* __restrict__ AO,
    int Sk, int causal)
{
    __shared__ __align__(16) bf16_t Ks[64 * 72];
    __shared__ __align__(16) bf16_t Vt[64 * 72];   // [d][k], pre-transposed
    __shared__ __align__(16) bf16_t Ps[64 * 72];

    int tid = threadIdx.x;
    int qt = blockIdx.x, bh = blockIdx.y;
    int w = tid >> 6, lane = tid & 63;
    int l15 = lane & 15, quad = lane >> 4;
    int wr = w << 4;
    int rowq = wr + (quad << 2);

    // Q fragments in registers
    const bf16_t* Qb = Q + ((long)bh * 1024 + (qt << 6)) * 64;
    bf16x8 aq0 = *(const bf16x8*)&Qb[(wr + l15) * 64 + (quad << 3)];
    bf16x8 aq1 = *(const bf16x8*)&Qb[(wr + l15) * 64 + (quad << 3) + 32];

    float m_i[4] = {-1e30f, -1e30f, -1e30f, -1e30f};
    float l_i[4] = {0.f, 0.f, 0.f, 0.f};
    f32x4 o_acc[4];
    for (int j = 0; j < 4; j++) o_acc[j] = (f32x4){0.f, 0.f, 0.f, 0.f};

    int nt = causal ? (qt + 1) : (Sk >> 6);
    long kb = (long)bh * Sk * 64;   // K head base
    long vb = (long)bh * 64 * Sk;   // V^T base

    int r = tid >> 2, c16 = (tid & 3) << 4;

    // preload tile 0 into registers
    bf16x8 kr0, kr1, vr0, vr1;
    {
        const bf16_t* kp = K + kb + (long)r * 64 + c16;
        const bf16_t* vp = V + vb + (long)r * Sk + c16;
        kr0 = *(const bf16x8*)kp;       kr1 = *(const bf16x8*)(kp + 8);
        vr0 = *(const bf16x8*)vp;       vr1 = *(const bf16x8*)(vp + 8);
    }

    for (int kt = 0; kt < nt; kt++) {
        __syncthreads();   // previous tile's Ks/Vt fully consumed
        *(bf16x8*)&Ks[r * 72 + c16]     = kr0;
        *(bf16x8*)&Ks[r * 72 + c16 + 8] = kr1;
        *(bf16x8*)&Vt[r * 72 + c16]     = vr0;
        *(bf16x8*)&Vt[r * 72 + c16 + 8] = vr1;
        if (kt + 1 < nt) {
            const bf16_t* kp = K + kb + (((long)(kt + 1) << 6) + r) * 64 + c16;
            const bf16_t* vp = V + vb + (long)r * Sk + ((kt + 1) << 6) + c16;
            kr0 = *(const bf16x8*)kp;   kr1 = *(const bf16x8*)(kp + 8);
            vr0 = *(const bf16x8*)vp;   vr1 = *(const bf16x8*)(vp + 8);
        }
        __syncthreads();

        // ---- scores: S = (Q K^T) * 0.125 ----
        f32x4 s[4];
        for (int j = 0; j < 4; j++) s[j] = (f32x4){0.f, 0.f, 0.f, 0.f};
        for (int j = 0; j < 4; j++) {
            bf16x8 bk0 = *(const bf16x8*)&Ks[((j << 4) + l15) * 72 + (quad << 3)];
            bf16x8 bk1 = *(const bf16x8*)&Ks[((j << 4) + l15) * 72 + (quad << 3) + 32];
            s[j] = __builtin_amdgcn_mfma_f32_16x16x32_bf16(aq0, bk0, s[j], 0, 0, 0);
            s[j] = __builtin_amdgcn_mfma_f32_16x16x32_bf16(aq1, bk1, s[j], 0, 0, 0);
        }

        // ---- online softmax (rows rowq..rowq+3, cols j*16+l15) ----
        int diag = causal && (kt == qt);
        for (int rr = 0; rr < 4; rr++) {
            float sv[4];
            for (int j = 0; j < 4; j++) {
                float x = s[j][rr] * 0.125f;
                if (diag && ((j << 4) + l15 > rowq + rr)) x = -1e30f;
                sv[j] = x;
            }
            float mx = fmaxf(fmaxf(sv[0], sv[1]), fmaxf(sv[2], sv[3]));
            for (int off = 1; off < 16; off <<= 1) mx = fmaxf(mx, __shfl_xor(mx, off));
            float mnew = fmaxf(m_i[rr], mx);
            float alpha = __expf(m_i[rr] - mnew);
            float p0 = __expf(sv[0] - mnew), p1 = __expf(sv[1] - mnew);
            float p2 = __expf(sv[2] - mnew), p3 = __expf(sv[3] - mnew);
            float rsum = p0 + p1 + p2 + p3;
            for (int off = 1; off < 16; off <<= 1) rsum += __shfl_xor(rsum, off);
            m_i[rr] = mnew;
            l_i[rr] = l_i[rr] * alpha + rsum;
            for (int j = 0; j < 4; j++) o_acc[j][rr] *= alpha;
            bf16_t* pr = &Ps[(rowq + rr) * 72 + l15];
            pr[0]  = (bf16_t)p0; pr[16] = (bf16_t)p1;
            pr[32] = (bf16_t)p2; pr[48] = (bf16_t)p3;
        }
        // Ps rows are wave-local: no s_barrier needed, but the ds_writes
        // must complete & not be reordered past the ds_reads below.
        asm volatile("s_waitcnt lgkmcnt(0)" ::: "memory");
        __builtin_amdgcn_sched_barrier(0);

        // ---- O += P V ----
        for (int ks = 0; ks < 2; ks++) {
            int sl = (quad + (ks << 2)) << 3;
            bf16x8 ap = *(const bf16x8*)&Ps[(wr + l15) * 72 + sl];
            for (int j = 0; j < 4; j++) {
                bf16x8 bv = *(const bf16x8*)&Vt[((j << 4) + l15) * 72 + sl];
                o_acc[j] = __builtin_amdgcn_mfma_f32_16x16x32_bf16(ap, bv, o_acc[j], 0, 0, 0);
            }
        }
    }

    bf16_t* Ob = AO + ((long)bh * 1024 + (qt << 6)) * 64;
    for (int rr = 0; rr < 4; rr++) {
        float inv = 1.0f / l_i[rr];
        for (int j = 0; j < 4; j++)
            Ob[(rowq + rr) * 64 + (j << 4) + l15] = (bf16_t)(o_acc[j][rr] * inv);
    }
}

// ---------------------------------------------------------------------------
// LEGACY flash attention (fallback path). Unchanged (known passing).
// ---------------------------------------------------------------------------
__global__ __launch_bounds__(256) void attn_kernel(
    const bf16_t* __restrict__ Q, const void* __restrict__ K,
    const void* __restrict__ V, bf16_t* __restrict__ AO,
    int Sk, int causal, int kv_f32)
{
    __shared__ __align__(16) bf16_t Qs[64 * 72];
    __shared__ __align__(16) bf16_t Ks[64 * 72];
    __shared__ __align__(16) bf16_t Vt[64 * 72];
    __shared__ __align__(16) bf16_t Ps[64 * 72];

    int tid = threadIdx.x;
    int qt = blockIdx.x, bh = blockIdx.y;
    int w = tid >> 6, lane = tid & 63;
    int l15 = lane & 15, quad = lane >> 4;
    int wr = w << 4;
    int rowq = wr + (quad << 2);

    {
        int r = tid >> 2, c16 = (tid & 3) << 4;
        const bf16_t* Qb = Q + ((long)bh * 1024 + qt * 64) * 64;
        bf16x8 a = *(const bf16x8*)&Qb[r * 64 + c16];
        bf16x8 b = *(const bf16x8*)&Qb[r * 64 + c16 + 8];
        *(bf16x8*)&Qs[r * 72 + c16] = a;
        *(bf16x8*)&Qs[r * 72 + c16 + 8] = b;
    }

    float m_i[4] = {-1e30f, -1e30f, -1e30f, -1e30f};
    float l_i[4] = {0.f, 0.f, 0.f, 0.f};
    f32x4 o_acc[4];
    for (int j = 0; j < 4; j++) o_acc[j] = (f32x4){0.f, 0.f, 0.f, 0.f};

    int nt = causal ? (qt + 1) : (Sk >> 6);
    long kvbase = (long)bh * Sk * 64;

    for (int kt = 0; kt < nt; kt++) {
        __syncthreads();
        {
            int r = tid >> 2, c16 = (tid & 3) << 4;
            long off = kvbase + (long)((kt << 6) + r) * 64 + c16;
            bf16x8 k0, k1, v0, v1;
            if (kv_f32) {
                const float* kp = (const float*)K + off;
                const float* vp = (const float*)V + off;
                k0 = load8f(kp); k1 = load8f(kp + 8);
                v0 = load8f(vp); v1 = load8f(vp + 8);
            } else {
                k0 = *(const bf16x8*)((const bf16_t*)K + off);
                k1 = *(const bf16x8*)((const bf16_t*)K + off + 8);
                v0 = *(const bf16x8*)((const bf16_t*)V + off);
                v1 = *(const bf16x8*)((const bf16_t*)V + off + 8);
            }
            *(bf16x8*)&Ks[r * 72 + c16] = k0;
            *(bf16x8*)&Ks[r * 72 + c16 + 8] = k1;
            for (int i = 0; i < 8; i++) {
                Vt[(c16 + i) * 72 + r]     = v0[i];
                Vt[(c16 + 8 + i) * 72 + r] = v1[i];
            }
        }
        __syncthreads();

        f32x4 s[4];
        for (int j = 0; j < 4; j++) s[j] = (f32x4){0.f, 0.f, 0.f, 0.f};
        for (int ks = 0; ks < 2; ks++) {
            int sl = (quad + (ks << 2)) << 3;
            bf16x8 aq = *(const bf16x8*)&Qs[(wr + l15) * 72 + sl];
            for (int j = 0; j < 4; j++) {
                bf16x8 bk = *(const bf16x8*)&Ks[((j << 4) + l15) * 72 + sl];
                s[j] = __builtin_amdgcn_mfma_f32_16x16x32_bf16(aq, bk, s[j], 0, 0, 0);
            }
        }

        int diag = causal && (kt == qt);
        for (int rr = 0; rr < 4; rr++) {
            float sv[4];
            for (int j = 0; j < 4; j++) {
                float x = s[j][rr] * 0.125f;
                if (diag && ((j << 4) + l15 > rowq + rr)) x = -1e30f;
                sv[j] = x;
            }
            float mx = fmaxf(fmaxf(sv[0], sv[1]), fmaxf(sv[2], sv[3]));
            for (int off = 1; off < 16; off <<= 1) mx = fmaxf(mx, __shfl_xor(mx, off));
            float mnew = fmaxf(m_i[rr], mx);
            float alpha = __expf(m_i[rr] - mnew);
            float p0 = __expf(sv[0] - mnew), p1 = __expf(sv[1] - mnew);
            float p2 = __expf(sv[2] - mnew), p3 = __expf(sv[3] - mnew);
            float rsum = p0 + p1 + p2 + p3;
            for (int off = 1; off < 16; off <<= 1) rsum += __shfl_xor(rsum, off);
            m_i[rr] = mnew;
            l_i[rr] = l_i[rr] * alpha + rsum;
            for (int j = 0; j < 4; j++) o_acc[j][rr] *= alpha;
            bf16_t* pr = &Ps[(rowq + rr) * 72 + l15];
            pr[0]  = (bf16_t)p0; pr[16] = (bf16_t)p1;
            pr[32] = (bf16_t)p2; pr[48] = (bf16_t)p3;
        }
        __syncthreads();

        for (int ks = 0; ks < 2; ks++) {
            int sl = (quad + (ks << 2)) << 3;
            bf16x8 ap = *(const bf16x8*)&Ps[(wr + l15) * 72 + sl];
            for (int j = 0; j < 4; j++) {
                bf16x8 bv = *(const bf16x8*)&Vt[((j << 4) + l15) * 72 + sl];
                o_acc[j] = __builtin_amdgcn_mfma_f32_16x16x32_bf16(ap, bv, o_acc[j], 0, 0, 0);
            }
        }
    }

    bf16_t* Ob = AO + ((long)bh * 1024 + qt * 64) * 64;
    for (int rr = 0; rr < 4; rr++) {
        float inv = 1.0f / l_i[rr];
        for (int j = 0; j < 4; j++)
            Ob[(rowq + rr) * 64 + (j << 4) + l15] = (bf16_t)(o_acc[j][rr] * inv);
    }
}

// ---------------------------------------------------------------------------
extern "C" void kernel_launch(void* const* d_in, const int* in_sizes, int n_in,
                              void* d_out, int out_size, void* d_ws, size_t ws_size,
                              hipStream_t stream)
{
    (void)in_sizes; (void)n_in; (void)out_size;
    const float* tgt       = (const float*)d_in[0];
    const float* mem       = (const float*)d_in[1];
    const float* Wq        = (const float*)d_in[2];
    const float* Wk        = (const float*)d_in[3];
    const float* Wv        = (const float*)d_in[4];
    const float* Wo        = (const float*)d_in[5];
    const float* mha_in_w  = (const float*)d_in[6];
    const float* mha_in_b  = (const float*)d_in[7];
    const float* mha_out_w = (const float*)d_in[8];
    const float* mha_out_b = (const float*)d_in[9];
    const float* W1        = (const float*)d_in[10];
    const float* b1        = (const float*)d_in[11];
    const float* W2        = (const float*)d_in[12];
    const float* b2        = (const float*)d_in[13];
    const float* g1        = (const float*)d_in[14];
    const float* be1       = (const float*)d_in[15];
    const float* g2        = (const float*)d_in[16];
    const float* be2       = (const float*)d_in[17];
    const float* g3        = (const float*)d_in[18];
    const float* be3       = (const float*)d_in[19];

    float* out_x = (float*)d_out;
    float* out_k = out_x + (1 << 22);
    float* out_v = out_k + (1 << 22);

    bf16_t* R0 = (bf16_t*)d_ws;
    bf16_t* R1 = R0 + (1 << 22);
    bf16_t* R2 = R1 + (1 << 22);

    dim3 blk(256);
    dim3 blk5(512);
    dim3 gA(16, 64);

    if (ws_size >= ((size_t)96 << 20)) {
        // ---------------- FAST PATH ----------------
        bf16_t* Hff  = R2 + (1 << 22);                              // [24,56) MB
        bf16_t* Wb   = (bf16_t*)((char*)d_ws + ((size_t)56 << 20)); // [56,88)
        bf16_t* memb = Wb + 16777216;                               // [88,96)
        bf16_t* saKb = Hff;                 // [24,32) MB — bf16 K head
        bf16_t* saVb = Hff + (1 << 22);     // [32,40) MB — bf16 V TRANSPOSED
        const long WO_OFF  = 3145728;
        const long CQ_OFF  = 4194304;
        const long CKV_OFF = 5242880;
        const long CO_OFF  = 7340032;
        const long W1_OFF  = 8388608;
        const long W2_OFF  = 12582912;

        conv_kernel<<<10240, blk, 0, stream>>>(Wq, Wk, Wv, Wo, mha_in_w,
                                               mha_out_w, W1, W2, mem, Wb);

        // ---- self-attention ----
        ln_kernel<<<4096, blk, 0, stream>>>(tgt, g1, be1, R0);
        gemm_big128<<<dim3(12, 32), blk5, 0, stream>>>(R0, 1024, Wb, 0, 1024, 1024,
                                                       nullptr, 0, nullptr,
                                                       R1, out_k, out_v, 1, 3072, 0,
                                                       saKb, saVb);
        attn_fast<<<gA, blk, 0, stream>>>(R1, saKb, saVb, R1, 1024, 1);
        gemm_fast<2><<<dim3(16, 32), blk, 0, stream>>>(R1, 0, 1, Wb, WO_OFF, 1024, 1024,
                                                       nullptr, 0, tgt,
                                                       out_x, nullptr, nullptr, 0, 1024, 0,
                                                       nullptr, nullptr);

        // ---- cross-attention ----
        ln_kernel<<<4096, blk, 0, stream>>>(out_x, g2, be2, R0);
        gemm_fast<2><<<dim3(16, 32), blk, 0, stream>>>(R0, 1024, 0, Wb, CQ_OFF, 1024, 1024,
                                                       mha_in_b, 0, nullptr,
                                                       nullptr, nullptr, R1, 0, 1024, 0,
                                                       nullptr, nullptr);
        gemm_big128<<<dim3(8, 32), blk5, 0, stream>>>(memb, 1024, Wb, CKV_OFF, 1024, 1024,
                                                      mha_in_b, 1024, nullptr,
                                                      R2, R0, nullptr, 2, 2048, 0,
                                                      nullptr, nullptr);
        attn_fast<<<gA, blk, 0, stream>>>(R1, R2, R0, R1, 1024, 0);
        gemm_fast<2><<<dim3(16, 32), blk, 0, stream>>>(R1, 0, 1, Wb, CO_OFF, 1024, 1024,
                                                       mha_out_b, 0, out_x,
                                                       out_x, nullptr, nullptr, 0, 1024, 0,
                                                       nullptr, nullptr);

        // ---- FFN ----
        ln_kernel<<<4096, blk, 0, stream>>>(out_x, g3, be3, R0);
        gemm_big128<<<dim3(16, 32), blk5, 0, stream>>>(R0, 1024, Wb, W1_OFF, 1024, 1024,
                                                       b1, 0, nullptr,
                                                       nullptr, Hff, nullptr, 0, 4096, 1,
                                                       nullptr, nullptr);
        gemm_fast<2><<<dim3(16, 32), blk, 0, stream>>>(Hff, 4096, 0, Wb, W2_OFF, 4096, 4096,
                                                       b2, 0, out_x,
                                                       out_x, nullptr, nullptr, 0, 1024, 0,
                                                       nullptr, nullptr);
        return;
    }

    // ---------------- FALLBACK (round-5, known passing) ----------------
    dim3 gD(8, 32);
    dim3 gF1(32, 16);
    dim3 gF2(8, 16);

    ln_kernel<<<4096, blk, 0, stream>>>(tgt, g1, be1, R0);
    gemm_nt<<<gD, blk, 0, stream>>>(R0, 1024, 0, 0, Wq, 0, 1024, 1024,
                                    nullptr, 0, nullptr, nullptr, nullptr,
                                    nullptr, R1, 1024, 0);
    gemm_nt<<<gD, blk, 0, stream>>>(R0, 1024, 0, 0, Wk, 0, 1024, 1024,
                                    nullptr, 0, nullptr, nullptr, nullptr,
                                    out_k, nullptr, 1024, 0);
    gemm_nt<<<gD, blk, 0, stream>>>(R0, 1024, 0, 0, Wv, 0, 1024, 1024,
                                    nullptr, 0, nullptr, nullptr, nullptr,
                                    out_v, nullptr, 1024, 0);
    attn_kernel<<<gA, blk, 0, stream>>>(R1, out_k, out_v, R1, 1024, 1, 1);
    gemm_nt<<<gD, blk, 0, stream>>>(R1, 0, 1, 0, Wo, 0, 1024, 1024,
                                    nullptr, 0, tgt, out_x, nullptr,
                                    nullptr, nullptr, 1024, 0);

    ln_kernel<<<4096, blk, 0, stream>>>(out_x, g2, be2, R0);
    gemm_nt<<<gD, blk, 0, stream>>>(R0, 1024, 0, 0, mha_in_w, 0, 1024, 1024,
                                    mha_in_b, 0, nullptr, nullptr, nullptr,
                                    nullptr, R1, 1024, 0);
    gemm_nt<<<gD, blk, 0, stream>>>(mem, 1024, 0, 1, mha_in_w, (long)1 << 20, 1024, 1024,
                                    mha_in_b, 1024, nullptr, nullptr, nullptr,
                                    nullptr, R2, 1024, 0);
    gemm_nt<<<gD, blk, 0, stream>>>(mem, 1024, 0, 1, mha_in_w, (long)2 << 20, 1024, 1024,
                                    mha_in_b, 2048, nullptr, nullptr, nullptr,
                                    nullptr, R0, 1024, 0);
    attn_kernel<<<gA, blk, 0, stream>>>(R1, R2, R0, R1, 1024, 0, 0);
    gemm_nt<<<gD, blk, 0, stream>>>(R1, 0, 1, 0, mha_out_w, 0, 1024, 1024,
                                    mha_out_b, 0, out_x, out_x, nullptr,
                                    nullptr, nullptr, 1024, 0);

    ln_kernel<<<4096, blk, 0, stream>>>(out_x, g3, be3, R0);
    for (int c = 0; c < 2; c++) {
        const bf16_t* Ac = R0 + (long)c * 2048 * 1024;
        bf16_t*       Hc = R1;
        float*        Xc = out_x + (long)c * 2048 * 1024;
        gemm_nt<<<gF1, blk, 0, stream>>>(Ac, 1024, 0, 0, W1, 0, 1024, 1024,
                                         b1, 0, nullptr, nullptr, Hc,
                                         nullptr, nullptr, 4096, 1);
        gemm_nt<<<gF2, blk, 0, stream>>>(Hc, 4096, 0, 0, W2, 0, 4096, 4096,
                                         b2, 0, Xc, Xc, nullptr,
                                         nullptr, nullptr, 1024, 0);
    }
}